// Round 1
// baseline (1709.272 us; speedup 1.0000x reference)
//
#include <hip/hip_runtime.h>

#define N_NODES 100000
#define N_EDGES 1600000
#define IN_DIM 256
#define HID 64
#define N_GRAPHS 100

// ---------------- CSR build ----------------

__global__ void k_init_deg(int* __restrict__ deg) {
    int i = blockIdx.x * 256 + threadIdx.x;
    if (i < N_NODES) deg[i] = 1;  // self loop
}

__global__ void k_hist(const int* __restrict__ dst, int* __restrict__ deg) {
    int e = blockIdx.x * 256 + threadIdx.x;
    if (e < N_EDGES) atomicAdd(&deg[dst[e]], 1);
}

// per-block reduce of (deg-1) + dinv compute
__global__ void k_scan1(const int* __restrict__ deg, float* __restrict__ dinv,
                        int* __restrict__ bsum) {
    __shared__ int s[256];
    int t = threadIdx.x;
    int i = blockIdx.x * 256 + t;
    int c = 0;
    if (i < N_NODES) {
        int d = deg[i];
        dinv[i] = rsqrtf((float)d);
        c = d - 1;
    }
    s[t] = c; __syncthreads();
    for (int off = 128; off; off >>= 1) {
        if (t < off) s[t] += s[t + off];
        __syncthreads();
    }
    if (t == 0) bsum[blockIdx.x] = s[0];
}

// exclusive scan of block sums (nb <= 512), single block
__global__ void k_scan2(const int* __restrict__ bsum, int* __restrict__ bscan, int nb) {
    __shared__ int s[512];
    int t = threadIdx.x;
    int v = (t < nb) ? bsum[t] : 0;
    s[t] = v; __syncthreads();
    for (int off = 1; off < 512; off <<= 1) {
        int u = 0;
        if (t >= off) u = s[t - off];
        __syncthreads();
        s[t] += u;
        __syncthreads();
    }
    if (t < nb) bscan[t] = s[t] - v;
}

// per-block exclusive scan -> row_ptr, fill
__global__ void k_scan3(const int* __restrict__ deg, const int* __restrict__ bscan,
                        int* __restrict__ rowptr, int* __restrict__ fill) {
    __shared__ int s[256];
    int t = threadIdx.x;
    int i = blockIdx.x * 256 + t;
    int c = (i < N_NODES) ? deg[i] - 1 : 0;
    s[t] = c; __syncthreads();
    for (int off = 1; off < 256; off <<= 1) {
        int u = 0;
        if (t >= off) u = s[t - off];
        __syncthreads();
        s[t] += u;
        __syncthreads();
    }
    int pos = bscan[blockIdx.x] + s[t] - c;  // exclusive
    if (i < N_NODES) { rowptr[i] = pos; fill[i] = pos; }
}

__global__ void k_csr(const int* __restrict__ src, const int* __restrict__ dst,
                      const float* __restrict__ dinv, int* __restrict__ fill,
                      int* __restrict__ col, float* __restrict__ wgt) {
    int e = blockIdx.x * 256 + threadIdx.x;
    if (e >= N_EDGES) return;
    int s = src[e], d = dst[e];
    int pos = atomicAdd(&fill[d], 1);
    col[pos] = s;
    wgt[pos] = dinv[s] * dinv[d];
}

// ---------------- GEMM: T[N,64] = X[N,K] @ W[K,64] ----------------
// one wave -> 8 rows; W loads coalesced + reused over 8 rows; x loads wave-uniform (scalarizable)

template <int K>
__global__ __launch_bounds__(256) void k_gemm(const float* __restrict__ X,
                                              const float* __restrict__ W,
                                              float* __restrict__ T) {
    int lane = threadIdx.x & 63;
    int wv = threadIdx.x >> 6;
    int r0 = (blockIdx.x * 4 + wv) * 8;
    if (r0 >= N_NODES) return;
    float acc[8] = {0.f, 0.f, 0.f, 0.f, 0.f, 0.f, 0.f, 0.f};
    for (int k = 0; k < K; k += 4) {
        float w0 = W[(k + 0) * HID + lane];
        float w1 = W[(k + 1) * HID + lane];
        float w2 = W[(k + 2) * HID + lane];
        float w3 = W[(k + 3) * HID + lane];
#pragma unroll
        for (int r = 0; r < 8; ++r) {
            const float4 xv = *(const float4*)(X + (size_t)(r0 + r) * K + k);
            acc[r] = fmaf(xv.w, w3, fmaf(xv.z, w2, fmaf(xv.y, w1, fmaf(xv.x, w0, acc[r]))));
        }
    }
#pragma unroll
    for (int r = 0; r < 8; ++r) T[(size_t)(r0 + r) * HID + lane] = acc[r];
}

// ---------------- aggregation: H[i] = b + dinv[i]^2*T[i] + sum_e w*T[src] ----------------
// one wave per node, lane = feature column

__global__ __launch_bounds__(256) void k_agg(const float* __restrict__ T,
                                             const int* __restrict__ rowptr,
                                             const int* __restrict__ deg,
                                             const float* __restrict__ dinv,
                                             const int* __restrict__ col,
                                             const float* __restrict__ wgt,
                                             const float* __restrict__ bias,
                                             float* __restrict__ H, int relu) {
    int lane = threadIdx.x & 63;
    int node = blockIdx.x * 4 + (threadIdx.x >> 6);
    if (node >= N_NODES) return;
    float di = dinv[node];
    float acc = di * di * T[(size_t)node * HID + lane];
    int start = rowptr[node];
    int cnt = deg[node] - 1;
    for (int e = 0; e < cnt; ++e) {
        int s = col[start + e];
        float w = wgt[start + e];
        acc = fmaf(w, T[(size_t)s * HID + lane], acc);
    }
    float v = acc + bias[lane];
    if (relu) v = fmaxf(v, 0.f);
    H[(size_t)node * HID + lane] = v;
}

// ---------------- pooling + final linear ----------------

__global__ void k_initout(const float* __restrict__ bl, float* __restrict__ out) {
    int g = threadIdx.x;
    if (g < N_GRAPHS) out[g] = bl[0];
}

__global__ __launch_bounds__(256) void k_pool(const float* __restrict__ H,
                                              const float* __restrict__ Wl,
                                              const int* __restrict__ batch,
                                              float* __restrict__ out) {
    int lane = threadIdx.x & 63;
    int node = blockIdx.x * 4 + (threadIdx.x >> 6);
    if (node >= N_NODES) return;
    float v = H[(size_t)node * HID + lane] * Wl[lane];
    v += __shfl_down(v, 32);
    v += __shfl_down(v, 16);
    v += __shfl_down(v, 8);
    v += __shfl_down(v, 4);
    v += __shfl_down(v, 2);
    v += __shfl_down(v, 1);
    if (lane == 0) atomicAdd(&out[batch[node]], v);
}

extern "C" void kernel_launch(void* const* d_in, const int* in_sizes, int n_in,
                              void* d_out, int out_size, void* d_ws, size_t ws_size,
                              hipStream_t stream) {
    const float* x     = (const float*)d_in[0];
    const int*   ei    = (const int*)d_in[1];
    const int*   batch = (const int*)d_in[2];
    const float* W1    = (const float*)d_in[3];
    const float* b1    = (const float*)d_in[4];
    const float* W2    = (const float*)d_in[5];
    const float* b2    = (const float*)d_in[6];
    const float* W3    = (const float*)d_in[7];
    const float* b3    = (const float*)d_in[8];
    const float* Wl    = (const float*)d_in[9];
    const float* bl    = (const float*)d_in[10];
    float* out = (float*)d_out;

    char* p = (char*)d_ws;
    float* t      = (float*)p; p += (size_t)N_NODES * HID * 4;
    float* hA     = (float*)p; p += (size_t)N_NODES * HID * 4;
    int*   deg    = (int*)p;   p += (size_t)N_NODES * 4;
    float* dinv   = (float*)p; p += (size_t)N_NODES * 4;
    int*   rowptr = (int*)p;   p += (size_t)N_NODES * 4;
    int*   fill   = (int*)p;   p += (size_t)N_NODES * 4;
    int*   col    = (int*)p;   p += (size_t)N_EDGES * 4;
    float* wgt    = (float*)p; p += (size_t)N_EDGES * 4;
    int*   bsum   = (int*)p;   p += 512 * 4;
    int*   bscan  = (int*)p;   p += 512 * 4;

    const int* src  = ei;
    const int* dstp = ei + N_EDGES;

    const int nb = (N_NODES + 255) / 256;           // 391
    const int eb = (N_EDGES + 255) / 256;           // 6250
    const int gemm_blocks = N_NODES / 32;           // 3125
    const int node_wave_blocks = (N_NODES + 3) / 4; // 25000

    k_init_deg<<<nb, 256, 0, stream>>>(deg);
    k_hist<<<eb, 256, 0, stream>>>(dstp, deg);
    k_scan1<<<nb, 256, 0, stream>>>(deg, dinv, bsum);
    k_scan2<<<1, 512, 0, stream>>>(bsum, bscan, nb);
    k_scan3<<<nb, 256, 0, stream>>>(deg, bscan, rowptr, fill);
    k_csr<<<eb, 256, 0, stream>>>(src, dstp, dinv, fill, col, wgt);

    k_gemm<IN_DIM><<<gemm_blocks, 256, 0, stream>>>(x, W1, t);
    k_agg<<<node_wave_blocks, 256, 0, stream>>>(t, rowptr, deg, dinv, col, wgt, b1, hA, 1);
    k_gemm<HID><<<gemm_blocks, 256, 0, stream>>>(hA, W2, t);
    k_agg<<<node_wave_blocks, 256, 0, stream>>>(t, rowptr, deg, dinv, col, wgt, b2, hA, 1);
    k_gemm<HID><<<gemm_blocks, 256, 0, stream>>>(hA, W3, t);
    k_agg<<<node_wave_blocks, 256, 0, stream>>>(t, rowptr, deg, dinv, col, wgt, b3, hA, 0);

    k_initout<<<1, 128, 0, stream>>>(bl, out);
    k_pool<<<node_wave_blocks, 256, 0, stream>>>(hA, Wl, batch, out);
}

// Round 2
// 1154.749 us; speedup vs baseline: 1.4802x; 1.4802x over previous
//
#include <hip/hip_runtime.h>

#define N_NODES 100000
#define N_EDGES 1600000
#define IN_DIM 256
#define HID 64
#define N_GRAPHS 100
#define NPART 256   // partial buffers for pooling
#define PSTRIDE 128 // stride per partial buffer (>= N_GRAPHS)

// ---------------- CSR build ----------------

__global__ void k_init_deg(int* __restrict__ deg) {
    int i = blockIdx.x * 256 + threadIdx.x;
    if (i < N_NODES) deg[i] = 1;  // self loop
}

__global__ void k_hist(const int* __restrict__ dst, int* __restrict__ deg) {
    int e = blockIdx.x * 256 + threadIdx.x;
    if (e < N_EDGES) atomicAdd(&deg[dst[e]], 1);
}

__global__ void k_scan1(const int* __restrict__ deg, float* __restrict__ dinv,
                        int* __restrict__ bsum) {
    __shared__ int s[256];
    int t = threadIdx.x;
    int i = blockIdx.x * 256 + t;
    int c = 0;
    if (i < N_NODES) {
        int d = deg[i];
        dinv[i] = rsqrtf((float)d);
        c = d - 1;
    }
    s[t] = c; __syncthreads();
    for (int off = 128; off; off >>= 1) {
        if (t < off) s[t] += s[t + off];
        __syncthreads();
    }
    if (t == 0) bsum[blockIdx.x] = s[0];
}

__global__ void k_scan2(const int* __restrict__ bsum, int* __restrict__ bscan, int nb) {
    __shared__ int s[512];
    int t = threadIdx.x;
    int v = (t < nb) ? bsum[t] : 0;
    s[t] = v; __syncthreads();
    for (int off = 1; off < 512; off <<= 1) {
        int u = 0;
        if (t >= off) u = s[t - off];
        __syncthreads();
        s[t] += u;
        __syncthreads();
    }
    if (t < nb) bscan[t] = s[t] - v;
}

__global__ void k_scan3(const int* __restrict__ deg, const int* __restrict__ bscan,
                        int* __restrict__ rowptr, int* __restrict__ fill) {
    __shared__ int s[256];
    int t = threadIdx.x;
    int i = blockIdx.x * 256 + t;
    int c = (i < N_NODES) ? deg[i] - 1 : 0;
    s[t] = c; __syncthreads();
    for (int off = 1; off < 256; off <<= 1) {
        int u = 0;
        if (t >= off) u = s[t - off];
        __syncthreads();
        s[t] += u;
        __syncthreads();
    }
    int pos = bscan[blockIdx.x] + s[t] - c;  // exclusive
    if (i < N_NODES) { rowptr[i] = pos; fill[i] = pos; }
}

__global__ void k_csr(const int* __restrict__ src, const int* __restrict__ dst,
                      const float* __restrict__ dinv, int* __restrict__ fill,
                      int* __restrict__ col, float* __restrict__ wgt) {
    int e = blockIdx.x * 256 + threadIdx.x;
    if (e >= N_EDGES) return;
    int s = src[e], d = dst[e];
    int pos = atomicAdd(&fill[d], 1);
    col[pos] = s;
    wgt[pos] = dinv[s] * dinv[d];
}

// ---------------- GEMM: T[N,64] = X[N,K] @ W[K,64] ----------------

template <int K>
__global__ __launch_bounds__(256) void k_gemm(const float* __restrict__ X,
                                              const float* __restrict__ W,
                                              float* __restrict__ T) {
    int lane = threadIdx.x & 63;
    int wv = threadIdx.x >> 6;
    int r0 = (blockIdx.x * 4 + wv) * 8;
    if (r0 >= N_NODES) return;
    float acc[8] = {0.f, 0.f, 0.f, 0.f, 0.f, 0.f, 0.f, 0.f};
    for (int k = 0; k < K; k += 4) {
        float w0 = W[(k + 0) * HID + lane];
        float w1 = W[(k + 1) * HID + lane];
        float w2 = W[(k + 2) * HID + lane];
        float w3 = W[(k + 3) * HID + lane];
#pragma unroll
        for (int r = 0; r < 8; ++r) {
            const float4 xv = *(const float4*)(X + (size_t)(r0 + r) * K + k);
            acc[r] = fmaf(xv.w, w3, fmaf(xv.z, w2, fmaf(xv.y, w1, fmaf(xv.x, w0, acc[r]))));
        }
    }
#pragma unroll
    for (int r = 0; r < 8; ++r) T[(size_t)(r0 + r) * HID + lane] = acc[r];
}

// ---------------- aggregation ----------------

__global__ __launch_bounds__(256) void k_agg(const float* __restrict__ T,
                                             const int* __restrict__ rowptr,
                                             const int* __restrict__ deg,
                                             const float* __restrict__ dinv,
                                             const int* __restrict__ col,
                                             const float* __restrict__ wgt,
                                             const float* __restrict__ bias,
                                             float* __restrict__ H, int relu) {
    int lane = threadIdx.x & 63;
    int node = blockIdx.x * 4 + (threadIdx.x >> 6);
    if (node >= N_NODES) return;
    float di = dinv[node];
    float acc = di * di * T[(size_t)node * HID + lane];
    int start = rowptr[node];
    int cnt = deg[node] - 1;
    for (int e = 0; e < cnt; ++e) {
        int s = col[start + e];
        float w = wgt[start + e];
        acc = fmaf(w, T[(size_t)s * HID + lane], acc);
    }
    float v = acc + bias[lane];
    if (relu) v = fmaxf(v, 0.f);
    H[(size_t)node * HID + lane] = v;
}

// ---------------- pooling + final linear (two-level) ----------------

__global__ void k_zero_partial(float* __restrict__ partial) {
    int i = blockIdx.x * 256 + threadIdx.x;
    if (i < NPART * PSTRIDE) partial[i] = 0.f;
}

__global__ __launch_bounds__(256) void k_pool(const float* __restrict__ H,
                                              const float* __restrict__ Wl,
                                              const int* __restrict__ batch,
                                              float* __restrict__ partial) {
    int lane = threadIdx.x & 63;
    int node = blockIdx.x * 4 + (threadIdx.x >> 6);
    if (node >= N_NODES) return;
    float v = H[(size_t)node * HID + lane] * Wl[lane];
    v += __shfl_down(v, 32);
    v += __shfl_down(v, 16);
    v += __shfl_down(v, 8);
    v += __shfl_down(v, 4);
    v += __shfl_down(v, 2);
    v += __shfl_down(v, 1);
    if (lane == 0)
        atomicAdd(&partial[(blockIdx.x & (NPART - 1)) * PSTRIDE + batch[node]], v);
}

__global__ void k_pool_reduce(const float* __restrict__ partial,
                              const float* __restrict__ bl,
                              float* __restrict__ out) {
    int g = threadIdx.x;
    if (g >= N_GRAPHS) return;
    float s = bl[0];
    for (int p = 0; p < NPART; ++p) s += partial[p * PSTRIDE + g];
    out[g] = s;
}

extern "C" void kernel_launch(void* const* d_in, const int* in_sizes, int n_in,
                              void* d_out, int out_size, void* d_ws, size_t ws_size,
                              hipStream_t stream) {
    const float* x     = (const float*)d_in[0];
    const int*   ei    = (const int*)d_in[1];
    const int*   batch = (const int*)d_in[2];
    const float* W1    = (const float*)d_in[3];
    const float* b1    = (const float*)d_in[4];
    const float* W2    = (const float*)d_in[5];
    const float* b2    = (const float*)d_in[6];
    const float* W3    = (const float*)d_in[7];
    const float* b3    = (const float*)d_in[8];
    const float* Wl    = (const float*)d_in[9];
    const float* bl    = (const float*)d_in[10];
    float* out = (float*)d_out;

    char* p = (char*)d_ws;
    float* t       = (float*)p; p += (size_t)N_NODES * HID * 4;
    float* hA      = (float*)p; p += (size_t)N_NODES * HID * 4;
    int*   deg     = (int*)p;   p += (size_t)N_NODES * 4;
    float* dinv    = (float*)p; p += (size_t)N_NODES * 4;
    int*   rowptr  = (int*)p;   p += (size_t)N_NODES * 4;
    int*   fill    = (int*)p;   p += (size_t)N_NODES * 4;
    int*   col     = (int*)p;   p += (size_t)N_EDGES * 4;
    float* wgt     = (float*)p; p += (size_t)N_EDGES * 4;
    int*   bsum    = (int*)p;   p += 512 * 4;
    int*   bscan   = (int*)p;   p += 512 * 4;
    float* partial = (float*)p; p += (size_t)NPART * PSTRIDE * 4;

    const int* src  = ei;
    const int* dstp = ei + N_EDGES;

    const int nb = (N_NODES + 255) / 256;           // 391
    const int eb = (N_EDGES + 255) / 256;           // 6250
    const int gemm_blocks = N_NODES / 32;           // 3125
    const int node_wave_blocks = (N_NODES + 3) / 4; // 25000

    k_init_deg<<<nb, 256, 0, stream>>>(deg);
    k_hist<<<eb, 256, 0, stream>>>(dstp, deg);
    k_scan1<<<nb, 256, 0, stream>>>(deg, dinv, bsum);
    k_scan2<<<1, 512, 0, stream>>>(bsum, bscan, nb);
    k_scan3<<<nb, 256, 0, stream>>>(deg, bscan, rowptr, fill);
    k_csr<<<eb, 256, 0, stream>>>(src, dstp, dinv, fill, col, wgt);

    k_gemm<IN_DIM><<<gemm_blocks, 256, 0, stream>>>(x, W1, t);
    k_agg<<<node_wave_blocks, 256, 0, stream>>>(t, rowptr, deg, dinv, col, wgt, b1, hA, 1);
    k_gemm<HID><<<gemm_blocks, 256, 0, stream>>>(hA, W2, t);
    k_agg<<<node_wave_blocks, 256, 0, stream>>>(t, rowptr, deg, dinv, col, wgt, b2, hA, 1);
    k_gemm<HID><<<gemm_blocks, 256, 0, stream>>>(hA, W3, t);
    k_agg<<<node_wave_blocks, 256, 0, stream>>>(t, rowptr, deg, dinv, col, wgt, b3, hA, 0);

    k_zero_partial<<<(NPART * PSTRIDE + 255) / 256, 256, 0, stream>>>(partial);
    k_pool<<<node_wave_blocks, 256, 0, stream>>>(hA, Wl, batch, partial);
    k_pool_reduce<<<1, 128, 0, stream>>>(partial, bl, out);
}

// Round 3
// 675.097 us; speedup vs baseline: 2.5319x; 1.7105x over previous
//
#include <hip/hip_runtime.h>

#define N_NODES 100000
#define N_EDGES 1600000
#define IN_DIM 256
#define HID 64
#define N_GRAPHS 100
#define NPART 256
#define PSTRIDE 128

// ---------------- CSR build ----------------

__global__ void k_init_deg(int* __restrict__ deg) {
    int i = blockIdx.x * 256 + threadIdx.x;
    if (i < N_NODES) deg[i] = 1;  // self loop
}

__global__ void k_hist(const int* __restrict__ dst, int* __restrict__ deg) {
    int e = blockIdx.x * 256 + threadIdx.x;
    if (e < N_EDGES) atomicAdd(&deg[dst[e]], 1);
}

__global__ void k_scan1(const int* __restrict__ deg, float* __restrict__ dinv,
                        int* __restrict__ bsum) {
    __shared__ int s[256];
    int t = threadIdx.x;
    int i = blockIdx.x * 256 + t;
    int c = 0;
    if (i < N_NODES) {
        int d = deg[i];
        dinv[i] = rsqrtf((float)d);
        c = d - 1;
    }
    s[t] = c; __syncthreads();
    for (int off = 128; off; off >>= 1) {
        if (t < off) s[t] += s[t + off];
        __syncthreads();
    }
    if (t == 0) bsum[blockIdx.x] = s[0];
}

__global__ void k_scan2(const int* __restrict__ bsum, int* __restrict__ bscan, int nb) {
    __shared__ int s[512];
    int t = threadIdx.x;
    int v = (t < nb) ? bsum[t] : 0;
    s[t] = v; __syncthreads();
    for (int off = 1; off < 512; off <<= 1) {
        int u = 0;
        if (t >= off) u = s[t - off];
        __syncthreads();
        s[t] += u;
        __syncthreads();
    }
    if (t < nb) bscan[t] = s[t] - v;
}

__global__ void k_scan3(const int* __restrict__ deg, const int* __restrict__ bscan,
                        int* __restrict__ rowptr, int* __restrict__ fill) {
    __shared__ int s[256];
    int t = threadIdx.x;
    int i = blockIdx.x * 256 + t;
    int c = (i < N_NODES) ? deg[i] - 1 : 0;
    s[t] = c; __syncthreads();
    for (int off = 1; off < 256; off <<= 1) {
        int u = 0;
        if (t >= off) u = s[t - off];
        __syncthreads();
        s[t] += u;
        __syncthreads();
    }
    int pos = bscan[blockIdx.x] + s[t] - c;  // exclusive
    if (i < N_NODES) { rowptr[i] = pos; fill[i] = pos; }
}

__global__ void k_csr(const int* __restrict__ src, const int* __restrict__ dst,
                      const float* __restrict__ dinv, int* __restrict__ fill,
                      int* __restrict__ col, float* __restrict__ wgt) {
    int e = blockIdx.x * 256 + threadIdx.x;
    if (e >= N_EDGES) return;
    int s = src[e], d = dst[e];
    int pos = atomicAdd(&fill[d], 1);
    col[pos] = s;
    wgt[pos] = dinv[s] * dinv[d];
}

// ---------------- GEMM: T[N,64] = X[N,K] @ W[K,64] ----------------
// LDS-tiled: 256-row x 64-col block tile, K-tile 32.
// X staged TRANSPOSED (Xt[k][row], pad 260) so compute reads are ds_read_b128.
// Each thread: 8 rows x 8 cols of acc -> per k: 4 b128 LDS reads + 64 FMAs (VALU-bound).

template <int K>
__global__ __launch_bounds__(256) void k_gemm(const float* __restrict__ X,
                                              const float* __restrict__ W,
                                              float* __restrict__ T) {
    __shared__ float Xt[32][260];   // 33.3 KB (pad 4 keeps b128 alignment, breaks conflicts)
    __shared__ float Ws[32][64];    // 8 KB
    const int t = threadIdx.x;
    const int tc = t & 7;           // col group: cols tc*8 .. tc*8+7
    const int tr = t >> 3;          // row group: rows tr*8 .. tr*8+7
    const int r0 = blockIdx.x * 256;

    float acc[8][8] = {};

    for (int k0 = 0; k0 < K; k0 += 32) {
        // stage X tile (transposed). 2048 float4 / 256 threads = 8 each, coalesced per row.
#pragma unroll
        for (int s = 0; s < 8; ++s) {
            int j = t + 256 * s;
            int row = j >> 3, kq = j & 7;
            float4 v = make_float4(0.f, 0.f, 0.f, 0.f);
            if (r0 + row < N_NODES)
                v = *(const float4*)(X + (size_t)(r0 + row) * K + k0 + kq * 4);
            Xt[kq * 4 + 0][row] = v.x;
            Xt[kq * 4 + 1][row] = v.y;
            Xt[kq * 4 + 2][row] = v.z;
            Xt[kq * 4 + 3][row] = v.w;
        }
        // stage W tile: contiguous 2048 floats
#pragma unroll
        for (int s = 0; s < 2; ++s) {
            int j = t + 256 * s;
            *((float4*)Ws + j) = *((const float4*)(W + (size_t)k0 * HID) + j);
        }
        __syncthreads();

#pragma unroll 4
        for (int k = 0; k < 32; ++k) {
            float4 a0 = *(const float4*)&Xt[k][tr * 8];
            float4 a1 = *(const float4*)&Xt[k][tr * 8 + 4];
            float4 w0 = *(const float4*)&Ws[k][tc * 8];
            float4 w1 = *(const float4*)&Ws[k][tc * 8 + 4];
            float ar[8] = {a0.x, a0.y, a0.z, a0.w, a1.x, a1.y, a1.z, a1.w};
            float wr[8] = {w0.x, w0.y, w0.z, w0.w, w1.x, w1.y, w1.z, w1.w};
#pragma unroll
            for (int i = 0; i < 8; ++i)
#pragma unroll
                for (int j = 0; j < 8; ++j)
                    acc[i][j] = fmaf(ar[i], wr[j], acc[i][j]);
        }
        __syncthreads();
    }

#pragma unroll
    for (int i = 0; i < 8; ++i) {
        int row = r0 + tr * 8 + i;
        if (row < N_NODES) {
            float4 o0 = make_float4(acc[i][0], acc[i][1], acc[i][2], acc[i][3]);
            float4 o1 = make_float4(acc[i][4], acc[i][5], acc[i][6], acc[i][7]);
            *(float4*)(T + (size_t)row * HID + tc * 8) = o0;
            *(float4*)(T + (size_t)row * HID + tc * 8 + 4) = o1;
        }
    }
}

// ---------------- aggregation: H[i] = b + dinv[i]^2*T[i] + sum_e w*T[src] ----------------
// one wave per node, lane = feature; 4-edge unroll for outstanding gathers

__global__ __launch_bounds__(256) void k_agg(const float* __restrict__ T,
                                             const int* __restrict__ rowptr,
                                             const int* __restrict__ deg,
                                             const float* __restrict__ dinv,
                                             const int* __restrict__ col,
                                             const float* __restrict__ wgt,
                                             const float* __restrict__ bias,
                                             float* __restrict__ H, int relu) {
    int lane = threadIdx.x & 63;
    int node = blockIdx.x * 4 + (threadIdx.x >> 6);
    if (node >= N_NODES) return;
    float di = dinv[node];
    float acc = di * di * T[(size_t)node * HID + lane];
    int e = rowptr[node];
    int end = e + deg[node] - 1;
    for (; e + 4 <= end; e += 4) {
        int s0 = col[e], s1 = col[e + 1], s2 = col[e + 2], s3 = col[e + 3];
        float w0 = wgt[e], w1 = wgt[e + 1], w2 = wgt[e + 2], w3 = wgt[e + 3];
        float t0 = T[(size_t)s0 * HID + lane];
        float t1 = T[(size_t)s1 * HID + lane];
        float t2 = T[(size_t)s2 * HID + lane];
        float t3 = T[(size_t)s3 * HID + lane];
        acc = fmaf(w0, t0, acc);
        acc = fmaf(w1, t1, acc);
        acc = fmaf(w2, t2, acc);
        acc = fmaf(w3, t3, acc);
    }
    for (; e < end; ++e)
        acc = fmaf(wgt[e], T[(size_t)col[e] * HID + lane], acc);
    float v = acc + bias[lane];
    if (relu) v = fmaxf(v, 0.f);
    H[(size_t)node * HID + lane] = v;
}

// layer-3 aggregation fused with pooling + final linear (no H write)
__global__ __launch_bounds__(256) void k_agg_pool(const float* __restrict__ T,
                                                  const int* __restrict__ rowptr,
                                                  const int* __restrict__ deg,
                                                  const float* __restrict__ dinv,
                                                  const int* __restrict__ col,
                                                  const float* __restrict__ wgt,
                                                  const float* __restrict__ bias,
                                                  const float* __restrict__ Wl,
                                                  const int* __restrict__ batch,
                                                  float* __restrict__ partial) {
    int lane = threadIdx.x & 63;
    int node = blockIdx.x * 4 + (threadIdx.x >> 6);
    if (node >= N_NODES) return;
    float di = dinv[node];
    float acc = di * di * T[(size_t)node * HID + lane];
    int e = rowptr[node];
    int end = e + deg[node] - 1;
    for (; e + 4 <= end; e += 4) {
        int s0 = col[e], s1 = col[e + 1], s2 = col[e + 2], s3 = col[e + 3];
        float w0 = wgt[e], w1 = wgt[e + 1], w2 = wgt[e + 2], w3 = wgt[e + 3];
        float t0 = T[(size_t)s0 * HID + lane];
        float t1 = T[(size_t)s1 * HID + lane];
        float t2 = T[(size_t)s2 * HID + lane];
        float t3 = T[(size_t)s3 * HID + lane];
        acc = fmaf(w0, t0, acc);
        acc = fmaf(w1, t1, acc);
        acc = fmaf(w2, t2, acc);
        acc = fmaf(w3, t3, acc);
    }
    for (; e < end; ++e)
        acc = fmaf(wgt[e], T[(size_t)col[e] * HID + lane], acc);
    float v = (acc + bias[lane]) * Wl[lane];
    v += __shfl_down(v, 32);
    v += __shfl_down(v, 16);
    v += __shfl_down(v, 8);
    v += __shfl_down(v, 4);
    v += __shfl_down(v, 2);
    v += __shfl_down(v, 1);
    if (lane == 0)
        atomicAdd(&partial[(blockIdx.x & (NPART - 1)) * PSTRIDE + batch[node]], v);
}

__global__ void k_zero_partial(float* __restrict__ partial) {
    int i = blockIdx.x * 256 + threadIdx.x;
    if (i < NPART * PSTRIDE) partial[i] = 0.f;
}

__global__ void k_pool_reduce(const float* __restrict__ partial,
                              const float* __restrict__ bl,
                              float* __restrict__ out) {
    int g = threadIdx.x;
    if (g >= N_GRAPHS) return;
    float s = bl[0];
    for (int p = 0; p < NPART; ++p) s += partial[p * PSTRIDE + g];
    out[g] = s;
}

extern "C" void kernel_launch(void* const* d_in, const int* in_sizes, int n_in,
                              void* d_out, int out_size, void* d_ws, size_t ws_size,
                              hipStream_t stream) {
    const float* x     = (const float*)d_in[0];
    const int*   ei    = (const int*)d_in[1];
    const int*   batch = (const int*)d_in[2];
    const float* W1    = (const float*)d_in[3];
    const float* b1    = (const float*)d_in[4];
    const float* W2    = (const float*)d_in[5];
    const float* b2    = (const float*)d_in[6];
    const float* W3    = (const float*)d_in[7];
    const float* b3    = (const float*)d_in[8];
    const float* Wl    = (const float*)d_in[9];
    const float* bl    = (const float*)d_in[10];
    float* out = (float*)d_out;

    char* p = (char*)d_ws;
    float* t       = (float*)p; p += (size_t)N_NODES * HID * 4;
    float* hA      = (float*)p; p += (size_t)N_NODES * HID * 4;
    int*   deg     = (int*)p;   p += (size_t)N_NODES * 4;
    float* dinv    = (float*)p; p += (size_t)N_NODES * 4;
    int*   rowptr  = (int*)p;   p += (size_t)N_NODES * 4;
    int*   fill    = (int*)p;   p += (size_t)N_NODES * 4;
    int*   col     = (int*)p;   p += (size_t)N_EDGES * 4;
    float* wgt     = (float*)p; p += (size_t)N_EDGES * 4;
    int*   bsum    = (int*)p;   p += 512 * 4;
    int*   bscan   = (int*)p;   p += 512 * 4;
    float* partial = (float*)p; p += (size_t)NPART * PSTRIDE * 4;

    const int* src  = ei;
    const int* dstp = ei + N_EDGES;

    const int nb = (N_NODES + 255) / 256;            // 391
    const int eb = (N_EDGES + 255) / 256;            // 6250
    const int gemm_blocks = (N_NODES + 255) / 256;   // 391
    const int node_wave_blocks = (N_NODES + 3) / 4;  // 25000

    k_init_deg<<<nb, 256, 0, stream>>>(deg);
    k_hist<<<eb, 256, 0, stream>>>(dstp, deg);
    k_scan1<<<nb, 256, 0, stream>>>(deg, dinv, bsum);
    k_scan2<<<1, 512, 0, stream>>>(bsum, bscan, nb);
    k_scan3<<<nb, 256, 0, stream>>>(deg, bscan, rowptr, fill);
    k_csr<<<eb, 256, 0, stream>>>(src, dstp, dinv, fill, col, wgt);

    k_zero_partial<<<(NPART * PSTRIDE + 255) / 256, 256, 0, stream>>>(partial);

    k_gemm<IN_DIM><<<gemm_blocks, 256, 0, stream>>>(x, W1, t);
    k_agg<<<node_wave_blocks, 256, 0, stream>>>(t, rowptr, deg, dinv, col, wgt, b1, hA, 1);
    k_gemm<HID><<<gemm_blocks, 256, 0, stream>>>(hA, W2, t);
    k_agg<<<node_wave_blocks, 256, 0, stream>>>(t, rowptr, deg, dinv, col, wgt, b2, hA, 1);
    k_gemm<HID><<<gemm_blocks, 256, 0, stream>>>(hA, W3, t);
    k_agg_pool<<<node_wave_blocks, 256, 0, stream>>>(t, rowptr, deg, dinv, col, wgt, b3,
                                                     Wl, batch, partial);

    k_pool_reduce<<<1, 128, 0, stream>>>(partial, bl, out);
}

// Round 4
// 567.969 us; speedup vs baseline: 3.0094x; 1.1886x over previous
//
#include <hip/hip_runtime.h>

#define N_NODES 100000
#define N_EDGES 1600000
#define IN_DIM 256
#define HID 64
#define N_GRAPHS 100
#define NPART 256
#define PSTRIDE 128
#define BSHIFT 8
#define NBUCK 391   // ceil(N_NODES / 256)
#define CHUNK 4096  // edges per block in bucket passes

// ---------------- bucketed edge partition ----------------

__global__ void k_zero_misc(int* __restrict__ bcount, float* __restrict__ partial) {
    int i = blockIdx.x * 256 + threadIdx.x;
    if (i < NBUCK) bcount[i] = 0;
    if (i < NPART * PSTRIDE) partial[i] = 0.f;
}

__global__ __launch_bounds__(256) void k_bhist(const int* __restrict__ dst,
                                               int* __restrict__ bcount) {
    __shared__ int lc[NBUCK];
    int t = threadIdx.x;
    for (int b = t; b < NBUCK; b += 256) lc[b] = 0;
    __syncthreads();
    int base = blockIdx.x * CHUNK;
#pragma unroll
    for (int i = 0; i < 16; ++i) {
        int e = base + i * 256 + t;
        if (e < N_EDGES) atomicAdd(&lc[dst[e] >> BSHIFT], 1);
    }
    __syncthreads();
    for (int b = t; b < NBUCK; b += 256)
        if (lc[b]) atomicAdd(&bcount[b], lc[b]);
}

// exclusive scan of bucket counts (NBUCK <= 512), also seeds bfill
__global__ void k_bscan(const int* __restrict__ bcount, int* __restrict__ bstart,
                        int* __restrict__ bfill) {
    __shared__ int s[512];
    int t = threadIdx.x;
    int v = (t < NBUCK) ? bcount[t] : 0;
    s[t] = v; __syncthreads();
    for (int off = 1; off < 512; off <<= 1) {
        int u = 0;
        if (t >= off) u = s[t - off];
        __syncthreads();
        s[t] += u;
        __syncthreads();
    }
    if (t < NBUCK) { int st = s[t] - v; bstart[t] = st; bfill[t] = st; }
    if (t == 0) bstart[NBUCK] = N_EDGES;
}

// scatter edges into bucket-contiguous array, packed (src<<8)|(dst&255)
__global__ __launch_bounds__(256) void k_bscatter(const int* __restrict__ src,
                                                  const int* __restrict__ dst,
                                                  int* __restrict__ bfill,
                                                  int* __restrict__ ebuck) {
    __shared__ int lc[NBUCK];
    __shared__ int lb[NBUCK];
    int t = threadIdx.x;
    for (int b = t; b < NBUCK; b += 256) lc[b] = 0;
    __syncthreads();
    int base = blockIdx.x * CHUNK;
    int pk[16], bk[16], rk[16];
#pragma unroll
    for (int i = 0; i < 16; ++i) {
        int e = base + i * 256 + t;
        rk[i] = -1;
        if (e < N_EDGES) {
            int s = src[e], d = dst[e];
            bk[i] = d >> BSHIFT;
            pk[i] = (s << BSHIFT) | (d & 255);
            rk[i] = atomicAdd(&lc[bk[i]], 1);
        }
    }
    __syncthreads();
    for (int b = t; b < NBUCK; b += 256)
        lb[b] = lc[b] ? atomicAdd(&bfill[b], lc[b]) : 0;
    __syncthreads();
#pragma unroll
    for (int i = 0; i < 16; ++i)
        if (rk[i] >= 0) ebuck[lb[bk[i]] + rk[i]] = pk[i];
}

// one block per bucket: degree via LDS histogram (no global atomics)
__global__ __launch_bounds__(256) void k_deg(const int* __restrict__ bstart,
                                             const int* __restrict__ ebuck,
                                             int* __restrict__ deg) {
    __shared__ int ld[256];
    int b = blockIdx.x, t = threadIdx.x;
    ld[t] = 1;  // self loop
    __syncthreads();
    int s = bstart[b], e = bstart[b + 1];
    for (int j = s + t; j < e; j += 256) atomicAdd(&ld[ebuck[j] & 255], 1);
    __syncthreads();
    int node = (b << BSHIFT) + t;
    if (node < N_NODES) deg[node] = ld[t];
}

// ---------------- rowptr scan ----------------

__global__ void k_scan1(const int* __restrict__ deg, float* __restrict__ dinv,
                        int* __restrict__ bsum) {
    __shared__ int s[256];
    int t = threadIdx.x;
    int i = blockIdx.x * 256 + t;
    int c = 0;
    if (i < N_NODES) {
        int d = deg[i];
        dinv[i] = rsqrtf((float)d);
        c = d - 1;
    }
    s[t] = c; __syncthreads();
    for (int off = 128; off; off >>= 1) {
        if (t < off) s[t] += s[t + off];
        __syncthreads();
    }
    if (t == 0) bsum[blockIdx.x] = s[0];
}

__global__ void k_scan2(const int* __restrict__ bsum, int* __restrict__ bscan, int nb) {
    __shared__ int s[512];
    int t = threadIdx.x;
    int v = (t < nb) ? bsum[t] : 0;
    s[t] = v; __syncthreads();
    for (int off = 1; off < 512; off <<= 1) {
        int u = 0;
        if (t >= off) u = s[t - off];
        __syncthreads();
        s[t] += u;
        __syncthreads();
    }
    if (t < nb) bscan[t] = s[t] - v;
}

__global__ void k_scan3(const int* __restrict__ deg, const int* __restrict__ bscan,
                        int* __restrict__ rowptr) {
    __shared__ int s[256];
    int t = threadIdx.x;
    int i = blockIdx.x * 256 + t;
    int c = (i < N_NODES) ? deg[i] - 1 : 0;
    s[t] = c; __syncthreads();
    for (int off = 1; off < 256; off <<= 1) {
        int u = 0;
        if (t >= off) u = s[t - off];
        __syncthreads();
        s[t] += u;
        __syncthreads();
    }
    if (i < N_NODES) rowptr[i] = bscan[blockIdx.x] + s[t] - c;  // exclusive
}

// one block per bucket: CSR fill into L2-resident rowptr window, packed {src, wgt}
__global__ __launch_bounds__(256) void k_fill(const int* __restrict__ bstart,
                                              const int* __restrict__ ebuck,
                                              const int* __restrict__ rowptr,
                                              const float* __restrict__ dinv,
                                              int2* __restrict__ epk) {
    __shared__ int lf[256];
    int b = blockIdx.x, t = threadIdx.x;
    int nbase = b << BSHIFT;
    int node = nbase + t;
    lf[t] = (node < N_NODES) ? rowptr[node] : 0;
    __syncthreads();
    int s = bstart[b], e = bstart[b + 1];
    for (int j = s + t; j < e; j += 256) {
        int v = ebuck[j];
        int srcn = v >> BSHIFT;
        int dl = v & 255;
        float w = dinv[srcn] * dinv[nbase + dl];
        int pos = atomicAdd(&lf[dl], 1);
        epk[pos] = make_int2(srcn, __float_as_int(w));
    }
}

// ---------------- GEMM: T[N,64] = X[N,K] @ W[K,64] ----------------

template <int K>
__global__ __launch_bounds__(256) void k_gemm(const float* __restrict__ X,
                                              const float* __restrict__ W,
                                              float* __restrict__ T) {
    __shared__ float Xt[32][260];
    __shared__ float Ws[32][64];
    const int t = threadIdx.x;
    const int tc = t & 7;
    const int tr = t >> 3;
    const int r0 = blockIdx.x * 256;

    float acc[8][8] = {};

    for (int k0 = 0; k0 < K; k0 += 32) {
#pragma unroll
        for (int s = 0; s < 8; ++s) {
            int j = t + 256 * s;
            int row = j >> 3, kq = j & 7;
            float4 v = make_float4(0.f, 0.f, 0.f, 0.f);
            if (r0 + row < N_NODES)
                v = *(const float4*)(X + (size_t)(r0 + row) * K + k0 + kq * 4);
            Xt[kq * 4 + 0][row] = v.x;
            Xt[kq * 4 + 1][row] = v.y;
            Xt[kq * 4 + 2][row] = v.z;
            Xt[kq * 4 + 3][row] = v.w;
        }
#pragma unroll
        for (int s = 0; s < 2; ++s) {
            int j = t + 256 * s;
            *((float4*)Ws + j) = *((const float4*)(W + (size_t)k0 * HID) + j);
        }
        __syncthreads();

#pragma unroll 4
        for (int k = 0; k < 32; ++k) {
            float4 a0 = *(const float4*)&Xt[k][tr * 8];
            float4 a1 = *(const float4*)&Xt[k][tr * 8 + 4];
            float4 w0 = *(const float4*)&Ws[k][tc * 8];
            float4 w1 = *(const float4*)&Ws[k][tc * 8 + 4];
            float ar[8] = {a0.x, a0.y, a0.z, a0.w, a1.x, a1.y, a1.z, a1.w};
            float wr[8] = {w0.x, w0.y, w0.z, w0.w, w1.x, w1.y, w1.z, w1.w};
#pragma unroll
            for (int i = 0; i < 8; ++i)
#pragma unroll
                for (int j = 0; j < 8; ++j)
                    acc[i][j] = fmaf(ar[i], wr[j], acc[i][j]);
        }
        __syncthreads();
    }

#pragma unroll
    for (int i = 0; i < 8; ++i) {
        int row = r0 + tr * 8 + i;
        if (row < N_NODES) {
            float4 o0 = make_float4(acc[i][0], acc[i][1], acc[i][2], acc[i][3]);
            float4 o1 = make_float4(acc[i][4], acc[i][5], acc[i][6], acc[i][7]);
            *(float4*)(T + (size_t)row * HID + tc * 8) = o0;
            *(float4*)(T + (size_t)row * HID + tc * 8 + 4) = o1;
        }
    }
}

// ---------------- aggregation ----------------

__global__ __launch_bounds__(256) void k_agg(const float* __restrict__ T,
                                             const int* __restrict__ rowptr,
                                             const int* __restrict__ deg,
                                             const float* __restrict__ dinv,
                                             const int2* __restrict__ epk,
                                             const float* __restrict__ bias,
                                             float* __restrict__ H, int relu) {
    int lane = threadIdx.x & 63;
    int node = blockIdx.x * 4 + (threadIdx.x >> 6);
    if (node >= N_NODES) return;
    float di = dinv[node];
    float acc = di * di * T[(size_t)node * HID + lane];
    int e = rowptr[node];
    int end = e + deg[node] - 1;
    for (; e + 4 <= end; e += 4) {
        int2 p0 = epk[e], p1 = epk[e + 1], p2 = epk[e + 2], p3 = epk[e + 3];
        float t0 = T[(size_t)p0.x * HID + lane];
        float t1 = T[(size_t)p1.x * HID + lane];
        float t2 = T[(size_t)p2.x * HID + lane];
        float t3 = T[(size_t)p3.x * HID + lane];
        acc = fmaf(__int_as_float(p0.y), t0, acc);
        acc = fmaf(__int_as_float(p1.y), t1, acc);
        acc = fmaf(__int_as_float(p2.y), t2, acc);
        acc = fmaf(__int_as_float(p3.y), t3, acc);
    }
    for (; e < end; ++e) {
        int2 pe = epk[e];
        acc = fmaf(__int_as_float(pe.y), T[(size_t)pe.x * HID + lane], acc);
    }
    float v = acc + bias[lane];
    if (relu) v = fmaxf(v, 0.f);
    H[(size_t)node * HID + lane] = v;
}

__global__ __launch_bounds__(256) void k_agg_pool(const float* __restrict__ T,
                                                  const int* __restrict__ rowptr,
                                                  const int* __restrict__ deg,
                                                  const float* __restrict__ dinv,
                                                  const int2* __restrict__ epk,
                                                  const float* __restrict__ bias,
                                                  const float* __restrict__ Wl,
                                                  const int* __restrict__ batch,
                                                  float* __restrict__ partial) {
    int lane = threadIdx.x & 63;
    int node = blockIdx.x * 4 + (threadIdx.x >> 6);
    if (node >= N_NODES) return;
    float di = dinv[node];
    float acc = di * di * T[(size_t)node * HID + lane];
    int e = rowptr[node];
    int end = e + deg[node] - 1;
    for (; e + 4 <= end; e += 4) {
        int2 p0 = epk[e], p1 = epk[e + 1], p2 = epk[e + 2], p3 = epk[e + 3];
        float t0 = T[(size_t)p0.x * HID + lane];
        float t1 = T[(size_t)p1.x * HID + lane];
        float t2 = T[(size_t)p2.x * HID + lane];
        float t3 = T[(size_t)p3.x * HID + lane];
        acc = fmaf(__int_as_float(p0.y), t0, acc);
        acc = fmaf(__int_as_float(p1.y), t1, acc);
        acc = fmaf(__int_as_float(p2.y), t2, acc);
        acc = fmaf(__int_as_float(p3.y), t3, acc);
    }
    for (; e < end; ++e) {
        int2 pe = epk[e];
        acc = fmaf(__int_as_float(pe.y), T[(size_t)pe.x * HID + lane], acc);
    }
    float v = (acc + bias[lane]) * Wl[lane];
    v += __shfl_down(v, 32);
    v += __shfl_down(v, 16);
    v += __shfl_down(v, 8);
    v += __shfl_down(v, 4);
    v += __shfl_down(v, 2);
    v += __shfl_down(v, 1);
    if (lane == 0)
        atomicAdd(&partial[(blockIdx.x & (NPART - 1)) * PSTRIDE + batch[node]], v);
}

__global__ void k_pool_reduce(const float* __restrict__ partial,
                              const float* __restrict__ bl,
                              float* __restrict__ out) {
    int g = threadIdx.x;
    if (g >= N_GRAPHS) return;
    float s = bl[0];
    for (int p = 0; p < NPART; ++p) s += partial[p * PSTRIDE + g];
    out[g] = s;
}

extern "C" void kernel_launch(void* const* d_in, const int* in_sizes, int n_in,
                              void* d_out, int out_size, void* d_ws, size_t ws_size,
                              hipStream_t stream) {
    const float* x     = (const float*)d_in[0];
    const int*   ei    = (const int*)d_in[1];
    const int*   batch = (const int*)d_in[2];
    const float* W1    = (const float*)d_in[3];
    const float* b1    = (const float*)d_in[4];
    const float* W2    = (const float*)d_in[5];
    const float* b2    = (const float*)d_in[6];
    const float* W3    = (const float*)d_in[7];
    const float* b3    = (const float*)d_in[8];
    const float* Wl    = (const float*)d_in[9];
    const float* bl    = (const float*)d_in[10];
    float* out = (float*)d_out;

    char* p = (char*)d_ws;
    float* t       = (float*)p; p += (size_t)N_NODES * HID * 4;   // 25.6 MB
    float* hA      = (float*)p; p += (size_t)N_NODES * HID * 4;   // 25.6 MB
    int2*  epk     = (int2*)p;  p += (size_t)N_EDGES * 8;         // 12.8 MB
    int*   ebuck   = (int*)p;   p += (size_t)N_EDGES * 4;         // 6.4 MB
    int*   deg     = (int*)p;   p += (size_t)N_NODES * 4;
    float* dinv    = (float*)p; p += (size_t)N_NODES * 4;
    int*   rowptr  = (int*)p;   p += (size_t)N_NODES * 4;
    int*   bcount  = (int*)p;   p += (NBUCK + 1) * 4;
    int*   bstart  = (int*)p;   p += (NBUCK + 1) * 4;
    int*   bfill   = (int*)p;   p += (NBUCK + 1) * 4;
    int*   bsum    = (int*)p;   p += 512 * 4;
    int*   bscan   = (int*)p;   p += 512 * 4;
    float* partial = (float*)p; p += (size_t)NPART * PSTRIDE * 4;

    const int* src  = ei;
    const int* dstp = ei + N_EDGES;

    const int nb = (N_NODES + 255) / 256;            // 391 (== NBUCK)
    const int cb = (N_EDGES + CHUNK - 1) / CHUNK;    // 391
    const int gemm_blocks = (N_NODES + 255) / 256;   // 391
    const int node_wave_blocks = (N_NODES + 3) / 4;  // 25000

    k_zero_misc<<<(NPART * PSTRIDE + 255) / 256, 256, 0, stream>>>(bcount, partial);
    k_bhist<<<cb, 256, 0, stream>>>(dstp, bcount);
    k_bscan<<<1, 512, 0, stream>>>(bcount, bstart, bfill);
    k_bscatter<<<cb, 256, 0, stream>>>(src, dstp, bfill, ebuck);
    k_deg<<<NBUCK, 256, 0, stream>>>(bstart, ebuck, deg);
    k_scan1<<<nb, 256, 0, stream>>>(deg, dinv, bsum);
    k_scan2<<<1, 512, 0, stream>>>(bsum, bscan, nb);
    k_scan3<<<nb, 256, 0, stream>>>(deg, bscan, rowptr);
    k_fill<<<NBUCK, 256, 0, stream>>>(bstart, ebuck, rowptr, dinv, epk);

    k_gemm<IN_DIM><<<gemm_blocks, 256, 0, stream>>>(x, W1, t);
    k_agg<<<node_wave_blocks, 256, 0, stream>>>(t, rowptr, deg, dinv, epk, b1, hA, 1);
    k_gemm<HID><<<gemm_blocks, 256, 0, stream>>>(hA, W2, t);
    k_agg<<<node_wave_blocks, 256, 0, stream>>>(t, rowptr, deg, dinv, epk, b2, hA, 1);
    k_gemm<HID><<<gemm_blocks, 256, 0, stream>>>(hA, W3, t);
    k_agg_pool<<<node_wave_blocks, 256, 0, stream>>>(t, rowptr, deg, dinv, epk, b3,
                                                     Wl, batch, partial);

    k_pool_reduce<<<1, 128, 0, stream>>>(partial, bl, out);
}

// Round 5
// 538.228 us; speedup vs baseline: 3.1757x; 1.0553x over previous
//
#include <hip/hip_runtime.h>

#define N_NODES 100000
#define N_EDGES 1600000
#define IN_DIM 256
#define HID 64
#define N_GRAPHS 100
#define NPART 256
#define PSTRIDE 128
#define BSHIFT 8
#define NBUCK 391   // ceil(N_NODES / 256)
#define CHUNK 4096  // edges per block in bucket passes

// ---------------- bucketed edge partition ----------------

__global__ void k_zero_misc(int* __restrict__ bcount, float* __restrict__ partial) {
    int i = blockIdx.x * 256 + threadIdx.x;
    if (i < NBUCK) bcount[i] = 0;
    if (i < NPART * PSTRIDE) partial[i] = 0.f;
}

__global__ __launch_bounds__(256) void k_bhist(const int* __restrict__ dst,
                                               int* __restrict__ bcount) {
    __shared__ int lc[NBUCK];
    int t = threadIdx.x;
    for (int b = t; b < NBUCK; b += 256) lc[b] = 0;
    __syncthreads();
    int base = blockIdx.x * CHUNK;
#pragma unroll
    for (int i = 0; i < 16; ++i) {
        int e = base + i * 256 + t;
        if (e < N_EDGES) atomicAdd(&lc[dst[e] >> BSHIFT], 1);
    }
    __syncthreads();
    for (int b = t; b < NBUCK; b += 256)
        if (lc[b]) atomicAdd(&bcount[b], lc[b]);
}

__global__ void k_bscan(const int* __restrict__ bcount, int* __restrict__ bstart,
                        int* __restrict__ bfill) {
    __shared__ int s[512];
    int t = threadIdx.x;
    int v = (t < NBUCK) ? bcount[t] : 0;
    s[t] = v; __syncthreads();
    for (int off = 1; off < 512; off <<= 1) {
        int u = 0;
        if (t >= off) u = s[t - off];
        __syncthreads();
        s[t] += u;
        __syncthreads();
    }
    if (t < NBUCK) { int st = s[t] - v; bstart[t] = st; bfill[t] = st; }
    if (t == 0) bstart[NBUCK] = N_EDGES;
}

__global__ __launch_bounds__(256) void k_bscatter(const int* __restrict__ src,
                                                  const int* __restrict__ dst,
                                                  int* __restrict__ bfill,
                                                  int* __restrict__ ebuck) {
    __shared__ int lc[NBUCK];
    __shared__ int lb[NBUCK];
    int t = threadIdx.x;
    for (int b = t; b < NBUCK; b += 256) lc[b] = 0;
    __syncthreads();
    int base = blockIdx.x * CHUNK;
    int pk[16], bk[16], rk[16];
#pragma unroll
    for (int i = 0; i < 16; ++i) {
        int e = base + i * 256 + t;
        rk[i] = -1;
        if (e < N_EDGES) {
            int s = src[e], d = dst[e];
            bk[i] = d >> BSHIFT;
            pk[i] = (s << BSHIFT) | (d & 255);
            rk[i] = atomicAdd(&lc[bk[i]], 1);
        }
    }
    __syncthreads();
    for (int b = t; b < NBUCK; b += 256)
        lb[b] = lc[b] ? atomicAdd(&bfill[b], lc[b]) : 0;
    __syncthreads();
#pragma unroll
    for (int i = 0; i < 16; ++i)
        if (rk[i] >= 0) ebuck[lb[bk[i]] + rk[i]] = pk[i];
}

__global__ __launch_bounds__(256) void k_deg(const int* __restrict__ bstart,
                                             const int* __restrict__ ebuck,
                                             int* __restrict__ deg) {
    __shared__ int ld[256];
    int b = blockIdx.x, t = threadIdx.x;
    ld[t] = 1;  // self loop
    __syncthreads();
    int s = bstart[b], e = bstart[b + 1];
    for (int j = s + t; j < e; j += 256) atomicAdd(&ld[ebuck[j] & 255], 1);
    __syncthreads();
    int node = (b << BSHIFT) + t;
    if (node < N_NODES) deg[node] = ld[t];
}

// ---------------- rowptr scan ----------------

__global__ void k_scan1(const int* __restrict__ deg, float* __restrict__ dinv,
                        int* __restrict__ bsum) {
    __shared__ int s[256];
    int t = threadIdx.x;
    int i = blockIdx.x * 256 + t;
    int c = 0;
    if (i < N_NODES) {
        int d = deg[i];
        dinv[i] = rsqrtf((float)d);
        c = d - 1;
    }
    s[t] = c; __syncthreads();
    for (int off = 128; off; off >>= 1) {
        if (t < off) s[t] += s[t + off];
        __syncthreads();
    }
    if (t == 0) bsum[blockIdx.x] = s[0];
}

__global__ void k_scan2(const int* __restrict__ bsum, int* __restrict__ bscan, int nb) {
    __shared__ int s[512];
    int t = threadIdx.x;
    int v = (t < nb) ? bsum[t] : 0;
    s[t] = v; __syncthreads();
    for (int off = 1; off < 512; off <<= 1) {
        int u = 0;
        if (t >= off) u = s[t - off];
        __syncthreads();
        s[t] += u;
        __syncthreads();
    }
    if (t < nb) bscan[t] = s[t] - v;
}

__global__ void k_scan3(const int* __restrict__ deg, const int* __restrict__ bscan,
                        int* __restrict__ rowptr) {
    __shared__ int s[256];
    int t = threadIdx.x;
    int i = blockIdx.x * 256 + t;
    int c = (i < N_NODES) ? deg[i] - 1 : 0;
    s[t] = c; __syncthreads();
    for (int off = 1; off < 256; off <<= 1) {
        int u = 0;
        if (t >= off) u = s[t - off];
        __syncthreads();
        s[t] += u;
        __syncthreads();
    }
    if (i < N_NODES) rowptr[i] = bscan[blockIdx.x] + s[t] - c;  // exclusive
}

__global__ __launch_bounds__(256) void k_fill(const int* __restrict__ bstart,
                                              const int* __restrict__ ebuck,
                                              const int* __restrict__ rowptr,
                                              const float* __restrict__ dinv,
                                              int2* __restrict__ epk) {
    __shared__ int lf[256];
    int b = blockIdx.x, t = threadIdx.x;
    int nbase = b << BSHIFT;
    int node = nbase + t;
    lf[t] = (node < N_NODES) ? rowptr[node] : 0;
    __syncthreads();
    int s = bstart[b], e = bstart[b + 1];
    for (int j = s + t; j < e; j += 256) {
        int v = ebuck[j];
        int srcn = v >> BSHIFT;
        int dl = v & 255;
        float w = dinv[srcn] * dinv[nbase + dl];
        int pos = atomicAdd(&lf[dl], 1);
        epk[pos] = make_int2(srcn, __float_as_int(w));
    }
}

// ---------------- GEMM: T[N,64] = X[N,K] @ W[K,64] ----------------
// 128-row x 64-col tile, K-tile 32, 782 blocks.
// Xt stored transposed with XOR row swizzle: X[r0+row][k0+kidx] lives at
// Xt[kidx][row ^ (((kidx>>2)&3)<<3)]. Verified bank math: staging writes and
// compute reads are <=2 lanes/bank (2-way aliasing is free on gfx950).
// Per thread: 8 rows x 4 cols acc; per k: 3 ds_read_b128 + 32 FMA (VALU-bound).

template <int K>
__global__ __launch_bounds__(256) void k_gemm(const float* __restrict__ X,
                                              const float* __restrict__ W,
                                              float* __restrict__ T) {
    __shared__ float Xt[32][132];   // 16.9 KB
    __shared__ float Ws[32][64];    // 8 KB
    const int t = threadIdx.x;
    const int tc = t & 15;          // col group: cols tc*4 .. tc*4+3
    const int tr = t >> 4;          // row group: rows tr*8 .. tr*8+7
    const int r0 = blockIdx.x * 128;

    float acc[8][4] = {};

    for (int k0 = 0; k0 < K; k0 += 32) {
        // stage X tile: 128 rows x 8 float4 = 1024 float4 / 256 threads = 4 each
#pragma unroll
        for (int s = 0; s < 4; ++s) {
            int j = t + 256 * s;
            int row = j >> 3, kq = j & 7;
            float4 v = make_float4(0.f, 0.f, 0.f, 0.f);
            if (r0 + row < N_NODES)
                v = *(const float4*)(X + (size_t)(r0 + row) * K + k0 + kq * 4);
            int xrow = row ^ ((kq & 3) << 3);
            Xt[kq * 4 + 0][xrow] = v.x;
            Xt[kq * 4 + 1][xrow] = v.y;
            Xt[kq * 4 + 2][xrow] = v.z;
            Xt[kq * 4 + 3][xrow] = v.w;
        }
        // stage W tile: 2048 floats = 512 float4 / 256 threads = 2 each
#pragma unroll
        for (int s = 0; s < 2; ++s) {
            int j = t + 256 * s;
            *((float4*)Ws + j) = *((const float4*)(W + (size_t)k0 * HID) + j);
        }
        __syncthreads();

#pragma unroll 4
        for (int k = 0; k < 32; ++k) {
            int base = (tr * 8) ^ (((k >> 2) & 3) << 3);
            float4 a0 = *(const float4*)&Xt[k][base];
            float4 a1 = *(const float4*)&Xt[k][base + 4];
            float4 wv = *(const float4*)&Ws[k][tc * 4];
            float ar[8] = {a0.x, a0.y, a0.z, a0.w, a1.x, a1.y, a1.z, a1.w};
#pragma unroll
            for (int i = 0; i < 8; ++i) {
                acc[i][0] = fmaf(ar[i], wv.x, acc[i][0]);
                acc[i][1] = fmaf(ar[i], wv.y, acc[i][1]);
                acc[i][2] = fmaf(ar[i], wv.z, acc[i][2]);
                acc[i][3] = fmaf(ar[i], wv.w, acc[i][3]);
            }
        }
        __syncthreads();
    }

#pragma unroll
    for (int i = 0; i < 8; ++i) {
        int row = r0 + tr * 8 + i;
        if (row < N_NODES) {
            float4 o = make_float4(acc[i][0], acc[i][1], acc[i][2], acc[i][3]);
            *(float4*)(T + (size_t)row * HID + tc * 4) = o;
        }
    }
}

// ---------------- aggregation ----------------

__global__ __launch_bounds__(256) void k_agg(const float* __restrict__ T,
                                             const int* __restrict__ rowptr,
                                             const int* __restrict__ deg,
                                             const float* __restrict__ dinv,
                                             const int2* __restrict__ epk,
                                             const float* __restrict__ bias,
                                             float* __restrict__ H, int relu) {
    int lane = threadIdx.x & 63;
    int node = blockIdx.x * 4 + (threadIdx.x >> 6);
    if (node >= N_NODES) return;
    float di = dinv[node];
    float acc = di * di * T[(size_t)node * HID + lane];
    int e = rowptr[node];
    int end = e + deg[node] - 1;
    for (; e + 4 <= end; e += 4) {
        int2 p0 = epk[e], p1 = epk[e + 1], p2 = epk[e + 2], p3 = epk[e + 3];
        float t0 = T[(size_t)p0.x * HID + lane];
        float t1 = T[(size_t)p1.x * HID + lane];
        float t2 = T[(size_t)p2.x * HID + lane];
        float t3 = T[(size_t)p3.x * HID + lane];
        acc = fmaf(__int_as_float(p0.y), t0, acc);
        acc = fmaf(__int_as_float(p1.y), t1, acc);
        acc = fmaf(__int_as_float(p2.y), t2, acc);
        acc = fmaf(__int_as_float(p3.y), t3, acc);
    }
    for (; e < end; ++e) {
        int2 pe = epk[e];
        acc = fmaf(__int_as_float(pe.y), T[(size_t)pe.x * HID + lane], acc);
    }
    float v = acc + bias[lane];
    if (relu) v = fmaxf(v, 0.f);
    H[(size_t)node * HID + lane] = v;
}

__global__ __launch_bounds__(256) void k_agg_pool(const float* __restrict__ T,
                                                  const int* __restrict__ rowptr,
                                                  const int* __restrict__ deg,
                                                  const float* __restrict__ dinv,
                                                  const int2* __restrict__ epk,
                                                  const float* __restrict__ bias,
                                                  const float* __restrict__ Wl,
                                                  const int* __restrict__ batch,
                                                  float* __restrict__ partial) {
    int lane = threadIdx.x & 63;
    int node = blockIdx.x * 4 + (threadIdx.x >> 6);
    if (node >= N_NODES) return;
    float di = dinv[node];
    float acc = di * di * T[(size_t)node * HID + lane];
    int e = rowptr[node];
    int end = e + deg[node] - 1;
    for (; e + 4 <= end; e += 4) {
        int2 p0 = epk[e], p1 = epk[e + 1], p2 = epk[e + 2], p3 = epk[e + 3];
        float t0 = T[(size_t)p0.x * HID + lane];
        float t1 = T[(size_t)p1.x * HID + lane];
        float t2 = T[(size_t)p2.x * HID + lane];
        float t3 = T[(size_t)p3.x * HID + lane];
        acc = fmaf(__int_as_float(p0.y), t0, acc);
        acc = fmaf(__int_as_float(p1.y), t1, acc);
        acc = fmaf(__int_as_float(p2.y), t2, acc);
        acc = fmaf(__int_as_float(p3.y), t3, acc);
    }
    for (; e < end; ++e) {
        int2 pe = epk[e];
        acc = fmaf(__int_as_float(pe.y), T[(size_t)pe.x * HID + lane], acc);
    }
    float v = (acc + bias[lane]) * Wl[lane];
    v += __shfl_down(v, 32);
    v += __shfl_down(v, 16);
    v += __shfl_down(v, 8);
    v += __shfl_down(v, 4);
    v += __shfl_down(v, 2);
    v += __shfl_down(v, 1);
    if (lane == 0)
        atomicAdd(&partial[(blockIdx.x & (NPART - 1)) * PSTRIDE + batch[node]], v);
}

__global__ void k_pool_reduce(const float* __restrict__ partial,
                              const float* __restrict__ bl,
                              float* __restrict__ out) {
    int g = threadIdx.x;
    if (g >= N_GRAPHS) return;
    float s = bl[0];
    for (int p = 0; p < NPART; ++p) s += partial[p * PSTRIDE + g];
    out[g] = s;
}

extern "C" void kernel_launch(void* const* d_in, const int* in_sizes, int n_in,
                              void* d_out, int out_size, void* d_ws, size_t ws_size,
                              hipStream_t stream) {
    const float* x     = (const float*)d_in[0];
    const int*   ei    = (const int*)d_in[1];
    const int*   batch = (const int*)d_in[2];
    const float* W1    = (const float*)d_in[3];
    const float* b1    = (const float*)d_in[4];
    const float* W2    = (const float*)d_in[5];
    const float* b2    = (const float*)d_in[6];
    const float* W3    = (const float*)d_in[7];
    const float* b3    = (const float*)d_in[8];
    const float* Wl    = (const float*)d_in[9];
    const float* bl    = (const float*)d_in[10];
    float* out = (float*)d_out;

    char* p = (char*)d_ws;
    float* t       = (float*)p; p += (size_t)N_NODES * HID * 4;
    float* hA      = (float*)p; p += (size_t)N_NODES * HID * 4;
    int2*  epk     = (int2*)p;  p += (size_t)N_EDGES * 8;
    int*   ebuck   = (int*)p;   p += (size_t)N_EDGES * 4;
    int*   deg     = (int*)p;   p += (size_t)N_NODES * 4;
    float* dinv    = (float*)p; p += (size_t)N_NODES * 4;
    int*   rowptr  = (int*)p;   p += (size_t)N_NODES * 4;
    int*   bcount  = (int*)p;   p += (NBUCK + 1) * 4;
    int*   bstart  = (int*)p;   p += (NBUCK + 1) * 4;
    int*   bfill   = (int*)p;   p += (NBUCK + 1) * 4;
    int*   bsum    = (int*)p;   p += 512 * 4;
    int*   bscan   = (int*)p;   p += 512 * 4;
    float* partial = (float*)p; p += (size_t)NPART * PSTRIDE * 4;

    const int* src  = ei;
    const int* dstp = ei + N_EDGES;

    const int nb = (N_NODES + 255) / 256;            // 391
    const int cb = (N_EDGES + CHUNK - 1) / CHUNK;    // 391
    const int gemm_blocks = (N_NODES + 127) / 128;   // 782
    const int node_wave_blocks = (N_NODES + 3) / 4;  // 25000

    k_zero_misc<<<(NPART * PSTRIDE + 255) / 256, 256, 0, stream>>>(bcount, partial);
    k_bhist<<<cb, 256, 0, stream>>>(dstp, bcount);
    k_bscan<<<1, 512, 0, stream>>>(bcount, bstart, bfill);
    k_bscatter<<<cb, 256, 0, stream>>>(src, dstp, bfill, ebuck);
    k_deg<<<NBUCK, 256, 0, stream>>>(bstart, ebuck, deg);
    k_scan1<<<nb, 256, 0, stream>>>(deg, dinv, bsum);
    k_scan2<<<1, 512, 0, stream>>>(bsum, bscan, nb);
    k_scan3<<<nb, 256, 0, stream>>>(deg, bscan, rowptr);
    k_fill<<<NBUCK, 256, 0, stream>>>(bstart, ebuck, rowptr, dinv, epk);

    k_gemm<IN_DIM><<<gemm_blocks, 256, 0, stream>>>(x, W1, t);
    k_agg<<<node_wave_blocks, 256, 0, stream>>>(t, rowptr, deg, dinv, epk, b1, hA, 1);
    k_gemm<HID><<<gemm_blocks, 256, 0, stream>>>(hA, W2, t);
    k_agg<<<node_wave_blocks, 256, 0, stream>>>(t, rowptr, deg, dinv, epk, b2, hA, 1);
    k_gemm<HID><<<gemm_blocks, 256, 0, stream>>>(hA, W3, t);
    k_agg_pool<<<node_wave_blocks, 256, 0, stream>>>(t, rowptr, deg, dinv, epk, b3,
                                                     Wl, batch, partial);

    k_pool_reduce<<<1, 128, 0, stream>>>(partial, bl, out);
}

// Round 6
// 476.468 us; speedup vs baseline: 3.5874x; 1.1296x over previous
//
#include <hip/hip_runtime.h>

#define N_NODES 100000
#define N_EDGES 1600000
#define IN_DIM 256
#define HID 64
#define N_GRAPHS 100
#define NPART 256
#define PSTRIDE 128
#define BSHIFT 8
#define NBUCK 391   // ceil(N_NODES / 256)
#define CHUNK 4096  // edges per block in bucket passes

// bf16 helpers (RNE)
__device__ __forceinline__ unsigned short f2b(float f) {
    unsigned int u = __float_as_uint(f);
    unsigned int r = (u + 0x7FFFu + ((u >> 16) & 1u)) >> 16;
    return (unsigned short)r;
}
__device__ __forceinline__ float b2f(unsigned short b) {
    return __uint_as_float(((unsigned int)b) << 16);
}

// ---------------- bucketed edge partition ----------------

__global__ void k_zero_misc(int* __restrict__ bcount, float* __restrict__ partial) {
    int i = blockIdx.x * 256 + threadIdx.x;
    if (i < NBUCK) bcount[i] = 0;
    if (i < NPART * PSTRIDE) partial[i] = 0.f;
}

__global__ __launch_bounds__(256) void k_bhist(const int* __restrict__ dst,
                                               int* __restrict__ bcount) {
    __shared__ int lc[NBUCK];
    int t = threadIdx.x;
    for (int b = t; b < NBUCK; b += 256) lc[b] = 0;
    __syncthreads();
    int base = blockIdx.x * CHUNK;
#pragma unroll
    for (int i = 0; i < 16; ++i) {
        int e = base + i * 256 + t;
        if (e < N_EDGES) atomicAdd(&lc[dst[e] >> BSHIFT], 1);
    }
    __syncthreads();
    for (int b = t; b < NBUCK; b += 256)
        if (lc[b]) atomicAdd(&bcount[b], lc[b]);
}

__global__ void k_bscan(const int* __restrict__ bcount, int* __restrict__ bstart,
                        int* __restrict__ bfill) {
    __shared__ int s[512];
    int t = threadIdx.x;
    int v = (t < NBUCK) ? bcount[t] : 0;
    s[t] = v; __syncthreads();
    for (int off = 1; off < 512; off <<= 1) {
        int u = 0;
        if (t >= off) u = s[t - off];
        __syncthreads();
        s[t] += u;
        __syncthreads();
    }
    if (t < NBUCK) { int st = s[t] - v; bstart[t] = st; bfill[t] = st; }
    if (t == 0) bstart[NBUCK] = N_EDGES;
}

__global__ __launch_bounds__(256) void k_bscatter(const int* __restrict__ src,
                                                  const int* __restrict__ dst,
                                                  int* __restrict__ bfill,
                                                  int* __restrict__ ebuck) {
    __shared__ int lc[NBUCK];
    __shared__ int lb[NBUCK];
    int t = threadIdx.x;
    for (int b = t; b < NBUCK; b += 256) lc[b] = 0;
    __syncthreads();
    int base = blockIdx.x * CHUNK;
    int pk[16], bk[16], rk[16];
#pragma unroll
    for (int i = 0; i < 16; ++i) {
        int e = base + i * 256 + t;
        rk[i] = -1;
        if (e < N_EDGES) {
            int s = src[e], d = dst[e];
            bk[i] = d >> BSHIFT;
            pk[i] = (s << BSHIFT) | (d & 255);
            rk[i] = atomicAdd(&lc[bk[i]], 1);
        }
    }
    __syncthreads();
    for (int b = t; b < NBUCK; b += 256)
        lb[b] = lc[b] ? atomicAdd(&bfill[b], lc[b]) : 0;
    __syncthreads();
#pragma unroll
    for (int i = 0; i < 16; ++i)
        if (rk[i] >= 0) ebuck[lb[bk[i]] + rk[i]] = pk[i];
}

__global__ __launch_bounds__(256) void k_deg(const int* __restrict__ bstart,
                                             const int* __restrict__ ebuck,
                                             int* __restrict__ deg) {
    __shared__ int ld[256];
    int b = blockIdx.x, t = threadIdx.x;
    ld[t] = 1;  // self loop
    __syncthreads();
    int s = bstart[b], e = bstart[b + 1];
    for (int j = s + t; j < e; j += 256) atomicAdd(&ld[ebuck[j] & 255], 1);
    __syncthreads();
    int node = (b << BSHIFT) + t;
    if (node < N_NODES) deg[node] = ld[t];
}

// ---------------- rowptr scan ----------------

__global__ void k_scan1(const int* __restrict__ deg, float* __restrict__ dinv,
                        int* __restrict__ bsum) {
    __shared__ int s[256];
    int t = threadIdx.x;
    int i = blockIdx.x * 256 + t;
    int c = 0;
    if (i < N_NODES) {
        int d = deg[i];
        dinv[i] = rsqrtf((float)d);
        c = d - 1;
    }
    s[t] = c; __syncthreads();
    for (int off = 128; off; off >>= 1) {
        if (t < off) s[t] += s[t + off];
        __syncthreads();
    }
    if (t == 0) bsum[blockIdx.x] = s[0];
}

__global__ void k_scan2(const int* __restrict__ bsum, int* __restrict__ bscan, int nb) {
    __shared__ int s[512];
    int t = threadIdx.x;
    int v = (t < nb) ? bsum[t] : 0;
    s[t] = v; __syncthreads();
    for (int off = 1; off < 512; off <<= 1) {
        int u = 0;
        if (t >= off) u = s[t - off];
        __syncthreads();
        s[t] += u;
        __syncthreads();
    }
    if (t < nb) bscan[t] = s[t] - v;
}

__global__ void k_scan3(const int* __restrict__ deg, const int* __restrict__ bscan,
                        int* __restrict__ rowptr) {
    __shared__ int s[256];
    int t = threadIdx.x;
    int i = blockIdx.x * 256 + t;
    int c = (i < N_NODES) ? deg[i] - 1 : 0;
    s[t] = c; __syncthreads();
    for (int off = 1; off < 256; off <<= 1) {
        int u = 0;
        if (t >= off) u = s[t - off];
        __syncthreads();
        s[t] += u;
        __syncthreads();
    }
    if (i < N_NODES) rowptr[i] = bscan[blockIdx.x] + s[t] - c;  // exclusive
}

__global__ __launch_bounds__(256) void k_fill(const int* __restrict__ bstart,
                                              const int* __restrict__ ebuck,
                                              const int* __restrict__ rowptr,
                                              const float* __restrict__ dinv,
                                              int2* __restrict__ epk) {
    __shared__ int lf[256];
    int b = blockIdx.x, t = threadIdx.x;
    int nbase = b << BSHIFT;
    int node = nbase + t;
    lf[t] = (node < N_NODES) ? rowptr[node] : 0;
    __syncthreads();
    int s = bstart[b], e = bstart[b + 1];
    for (int j = s + t; j < e; j += 256) {
        int v = ebuck[j];
        int srcn = v >> BSHIFT;
        int dl = v & 255;
        float w = dinv[srcn] * dinv[nbase + dl];
        int pos = atomicAdd(&lf[dl], 1);
        epk[pos] = make_int2(srcn, __float_as_int(w));
    }
}

// ---------------- GEMM: Tb[N,64](bf16) = X[N,K](fp32) @ W[K,64] ----------------
// 128x64 tile, K-tile 32, XOR-swizzled transposed X staging (<=2-way LDS aliasing).

template <int K>
__global__ __launch_bounds__(256) void k_gemm(const float* __restrict__ X,
                                              const float* __restrict__ W,
                                              unsigned short* __restrict__ Tb) {
    __shared__ float Xt[32][132];
    __shared__ float Ws[32][64];
    const int t = threadIdx.x;
    const int tc = t & 15;
    const int tr = t >> 4;
    const int r0 = blockIdx.x * 128;

    float acc[8][4] = {};

    for (int k0 = 0; k0 < K; k0 += 32) {
#pragma unroll
        for (int s = 0; s < 4; ++s) {
            int j = t + 256 * s;
            int row = j >> 3, kq = j & 7;
            float4 v = make_float4(0.f, 0.f, 0.f, 0.f);
            if (r0 + row < N_NODES)
                v = *(const float4*)(X + (size_t)(r0 + row) * K + k0 + kq * 4);
            int xrow = row ^ ((kq & 3) << 3);
            Xt[kq * 4 + 0][xrow] = v.x;
            Xt[kq * 4 + 1][xrow] = v.y;
            Xt[kq * 4 + 2][xrow] = v.z;
            Xt[kq * 4 + 3][xrow] = v.w;
        }
#pragma unroll
        for (int s = 0; s < 2; ++s) {
            int j = t + 256 * s;
            *((float4*)Ws + j) = *((const float4*)(W + (size_t)k0 * HID) + j);
        }
        __syncthreads();

#pragma unroll 4
        for (int k = 0; k < 32; ++k) {
            int base = (tr * 8) ^ (((k >> 2) & 3) << 3);
            float4 a0 = *(const float4*)&Xt[k][base];
            float4 a1 = *(const float4*)&Xt[k][base + 4];
            float4 wv = *(const float4*)&Ws[k][tc * 4];
            float ar[8] = {a0.x, a0.y, a0.z, a0.w, a1.x, a1.y, a1.z, a1.w};
#pragma unroll
            for (int i = 0; i < 8; ++i) {
                acc[i][0] = fmaf(ar[i], wv.x, acc[i][0]);
                acc[i][1] = fmaf(ar[i], wv.y, acc[i][1]);
                acc[i][2] = fmaf(ar[i], wv.z, acc[i][2]);
                acc[i][3] = fmaf(ar[i], wv.w, acc[i][3]);
            }
        }
        __syncthreads();
    }

#pragma unroll
    for (int i = 0; i < 8; ++i) {
        int row = r0 + tr * 8 + i;
        if (row < N_NODES) {
            ushort4 o;
            o.x = f2b(acc[i][0]); o.y = f2b(acc[i][1]);
            o.z = f2b(acc[i][2]); o.w = f2b(acc[i][3]);
            *(ushort4*)(Tb + (size_t)row * HID + tc * 4) = o;
        }
    }
}

// ---------------- aggregation: H[i] = b + dinv^2*Tb[i] + sum_e w*Tb[src] ----------------
// one wave per node, lane = feature; bf16 gathers (128 B/edge), scalar epk loads

__global__ __launch_bounds__(256) void k_agg(const unsigned short* __restrict__ Tb,
                                             const int* __restrict__ rowptr,
                                             const int* __restrict__ deg,
                                             const float* __restrict__ dinv,
                                             const int2* __restrict__ epk,
                                             const float* __restrict__ bias,
                                             float* __restrict__ H, int relu) {
    int lane = threadIdx.x & 63;
    int node = blockIdx.x * 4 + (threadIdx.x >> 6);
    float di = dinv[node];
    float acc0 = di * di * b2f(Tb[(size_t)node * HID + lane]);
    float acc1 = 0.f;
    int e   = __builtin_amdgcn_readfirstlane(rowptr[node]);
    int end = e + __builtin_amdgcn_readfirstlane(deg[node]) - 1;
    for (; e + 4 <= end; e += 4) {
        int2 p0 = epk[e], p1 = epk[e + 1], p2 = epk[e + 2], p3 = epk[e + 3];
        float t0 = b2f(Tb[(size_t)p0.x * HID + lane]);
        float t1 = b2f(Tb[(size_t)p1.x * HID + lane]);
        float t2 = b2f(Tb[(size_t)p2.x * HID + lane]);
        float t3 = b2f(Tb[(size_t)p3.x * HID + lane]);
        acc0 = fmaf(__int_as_float(p0.y), t0, acc0);
        acc1 = fmaf(__int_as_float(p1.y), t1, acc1);
        acc0 = fmaf(__int_as_float(p2.y), t2, acc0);
        acc1 = fmaf(__int_as_float(p3.y), t3, acc1);
    }
    for (; e < end; ++e) {
        int2 pe = epk[e];
        acc0 = fmaf(__int_as_float(pe.y), b2f(Tb[(size_t)pe.x * HID + lane]), acc0);
    }
    float v = acc0 + acc1 + bias[lane];
    if (relu) v = fmaxf(v, 0.f);
    H[(size_t)node * HID + lane] = v;
}

__global__ __launch_bounds__(256) void k_agg_pool(const unsigned short* __restrict__ Tb,
                                                  const int* __restrict__ rowptr,
                                                  const int* __restrict__ deg,
                                                  const float* __restrict__ dinv,
                                                  const int2* __restrict__ epk,
                                                  const float* __restrict__ bias,
                                                  const float* __restrict__ Wl,
                                                  const int* __restrict__ batch,
                                                  float* __restrict__ partial) {
    int lane = threadIdx.x & 63;
    int node = blockIdx.x * 4 + (threadIdx.x >> 6);
    float di = dinv[node];
    float acc0 = di * di * b2f(Tb[(size_t)node * HID + lane]);
    float acc1 = 0.f;
    int e   = __builtin_amdgcn_readfirstlane(rowptr[node]);
    int end = e + __builtin_amdgcn_readfirstlane(deg[node]) - 1;
    for (; e + 4 <= end; e += 4) {
        int2 p0 = epk[e], p1 = epk[e + 1], p2 = epk[e + 2], p3 = epk[e + 3];
        float t0 = b2f(Tb[(size_t)p0.x * HID + lane]);
        float t1 = b2f(Tb[(size_t)p1.x * HID + lane]);
        float t2 = b2f(Tb[(size_t)p2.x * HID + lane]);
        float t3 = b2f(Tb[(size_t)p3.x * HID + lane]);
        acc0 = fmaf(__int_as_float(p0.y), t0, acc0);
        acc1 = fmaf(__int_as_float(p1.y), t1, acc1);
        acc0 = fmaf(__int_as_float(p2.y), t2, acc0);
        acc1 = fmaf(__int_as_float(p3.y), t3, acc1);
    }
    for (; e < end; ++e) {
        int2 pe = epk[e];
        acc0 = fmaf(__int_as_float(pe.y), b2f(Tb[(size_t)pe.x * HID + lane]), acc0);
    }
    float v = (acc0 + acc1 + bias[lane]) * Wl[lane];
    v += __shfl_down(v, 32);
    v += __shfl_down(v, 16);
    v += __shfl_down(v, 8);
    v += __shfl_down(v, 4);
    v += __shfl_down(v, 2);
    v += __shfl_down(v, 1);
    if (lane == 0)
        atomicAdd(&partial[(blockIdx.x & (NPART - 1)) * PSTRIDE + batch[node]], v);
}

__global__ void k_pool_reduce(const float* __restrict__ partial,
                              const float* __restrict__ bl,
                              float* __restrict__ out) {
    int g = threadIdx.x;
    if (g >= N_GRAPHS) return;
    float s = bl[0];
    for (int p = 0; p < NPART; ++p) s += partial[p * PSTRIDE + g];
    out[g] = s;
}

extern "C" void kernel_launch(void* const* d_in, const int* in_sizes, int n_in,
                              void* d_out, int out_size, void* d_ws, size_t ws_size,
                              hipStream_t stream) {
    const float* x     = (const float*)d_in[0];
    const int*   ei    = (const int*)d_in[1];
    const int*   batch = (const int*)d_in[2];
    const float* W1    = (const float*)d_in[3];
    const float* b1    = (const float*)d_in[4];
    const float* W2    = (const float*)d_in[5];
    const float* b2    = (const float*)d_in[6];
    const float* W3    = (const float*)d_in[7];
    const float* b3    = (const float*)d_in[8];
    const float* Wl    = (const float*)d_in[9];
    const float* bl    = (const float*)d_in[10];
    float* out = (float*)d_out;

    char* p = (char*)d_ws;
    unsigned short* tb = (unsigned short*)p; p += (size_t)N_NODES * HID * 2;  // 12.8 MB
    float* hA      = (float*)p; p += (size_t)N_NODES * HID * 4;               // 25.6 MB
    int2*  epk     = (int2*)p;  p += (size_t)N_EDGES * 8;                     // 12.8 MB
    int*   ebuck   = (int*)p;   p += (size_t)N_EDGES * 4;                     // 6.4 MB
    int*   deg     = (int*)p;   p += (size_t)N_NODES * 4;
    float* dinv    = (float*)p; p += (size_t)N_NODES * 4;
    int*   rowptr  = (int*)p;   p += (size_t)N_NODES * 4;
    int*   bcount  = (int*)p;   p += (NBUCK + 1) * 4;
    int*   bstart  = (int*)p;   p += (NBUCK + 1) * 4;
    int*   bfill   = (int*)p;   p += (NBUCK + 1) * 4;
    int*   bsum    = (int*)p;   p += 512 * 4;
    int*   bscan   = (int*)p;   p += 512 * 4;
    float* partial = (float*)p; p += (size_t)NPART * PSTRIDE * 4;

    const int* src  = ei;
    const int* dstp = ei + N_EDGES;

    const int nb = (N_NODES + 255) / 256;            // 391
    const int cb = (N_EDGES + CHUNK - 1) / CHUNK;    // 391
    const int gemm_blocks = (N_NODES + 127) / 128;   // 782
    const int node_wave_blocks = (N_NODES + 3) / 4;  // 25000

    k_zero_misc<<<(NPART * PSTRIDE + 255) / 256, 256, 0, stream>>>(bcount, partial);
    k_bhist<<<cb, 256, 0, stream>>>(dstp, bcount);
    k_bscan<<<1, 512, 0, stream>>>(bcount, bstart, bfill);
    k_bscatter<<<cb, 256, 0, stream>>>(src, dstp, bfill, ebuck);
    k_deg<<<NBUCK, 256, 0, stream>>>(bstart, ebuck, deg);
    k_scan1<<<nb, 256, 0, stream>>>(deg, dinv, bsum);
    k_scan2<<<1, 512, 0, stream>>>(bsum, bscan, nb);
    k_scan3<<<nb, 256, 0, stream>>>(deg, bscan, rowptr);
    k_fill<<<NBUCK, 256, 0, stream>>>(bstart, ebuck, rowptr, dinv, epk);

    k_gemm<IN_DIM><<<gemm_blocks, 256, 0, stream>>>(x, W1, tb);
    k_agg<<<node_wave_blocks, 256, 0, stream>>>(tb, rowptr, deg, dinv, epk, b1, hA, 1);
    k_gemm<HID><<<gemm_blocks, 256, 0, stream>>>(hA, W2, tb);
    k_agg<<<node_wave_blocks, 256, 0, stream>>>(tb, rowptr, deg, dinv, epk, b2, hA, 1);
    k_gemm<HID><<<gemm_blocks, 256, 0, stream>>>(hA, W3, tb);
    k_agg_pool<<<node_wave_blocks, 256, 0, stream>>>(tb, rowptr, deg, dinv, epk, b3,
                                                     Wl, batch, partial);

    k_pool_reduce<<<1, 128, 0, stream>>>(partial, bl, out);
}

// Round 7
// 451.016 us; speedup vs baseline: 3.7898x; 1.0564x over previous
//
#include <hip/hip_runtime.h>

#define N_NODES 100000
#define N_EDGES 1600000
#define IN_DIM 256
#define HID 64
#define N_GRAPHS 100
#define NPART 256
#define PSTRIDE 128
#define BSHIFT 8
#define NBUCK 391   // ceil(N_NODES / 256)
#define CHUNK 4096  // edges per block in bucket passes

typedef __attribute__((ext_vector_type(8))) short short8;
typedef __attribute__((ext_vector_type(8))) unsigned short us8;
typedef __attribute__((ext_vector_type(4))) float floatx4;

// bf16 helpers (RNE)
__device__ __forceinline__ unsigned short f2b(float f) {
    unsigned int u = __float_as_uint(f);
    unsigned int r = (u + 0x7FFFu + ((u >> 16) & 1u)) >> 16;
    return (unsigned short)r;
}
__device__ __forceinline__ float b2f(unsigned short b) {
    return __uint_as_float(((unsigned int)b) << 16);
}

// ---------------- bucketed edge partition ----------------

__global__ void k_zero_misc(int* __restrict__ bcount, float* __restrict__ partial) {
    int i = blockIdx.x * 256 + threadIdx.x;
    if (i < NBUCK) bcount[i] = 0;
    if (i < NPART * PSTRIDE) partial[i] = 0.f;
}

__global__ __launch_bounds__(256) void k_bhist(const int* __restrict__ dst,
                                               int* __restrict__ bcount) {
    __shared__ int lc[NBUCK];
    int t = threadIdx.x;
    for (int b = t; b < NBUCK; b += 256) lc[b] = 0;
    __syncthreads();
    int base = blockIdx.x * CHUNK;
#pragma unroll
    for (int i = 0; i < 16; ++i) {
        int e = base + i * 256 + t;
        if (e < N_EDGES) atomicAdd(&lc[dst[e] >> BSHIFT], 1);
    }
    __syncthreads();
    for (int b = t; b < NBUCK; b += 256)
        if (lc[b]) atomicAdd(&bcount[b], lc[b]);
}

__global__ void k_bscan(const int* __restrict__ bcount, int* __restrict__ bstart,
                        int* __restrict__ bfill) {
    __shared__ int s[512];
    int t = threadIdx.x;
    int v = (t < NBUCK) ? bcount[t] : 0;
    s[t] = v; __syncthreads();
    for (int off = 1; off < 512; off <<= 1) {
        int u = 0;
        if (t >= off) u = s[t - off];
        __syncthreads();
        s[t] += u;
        __syncthreads();
    }
    if (t < NBUCK) { int st = s[t] - v; bstart[t] = st; bfill[t] = st; }
    if (t == 0) bstart[NBUCK] = N_EDGES;
}

__global__ __launch_bounds__(256) void k_bscatter(const int* __restrict__ src,
                                                  const int* __restrict__ dst,
                                                  int* __restrict__ bfill,
                                                  int* __restrict__ ebuck) {
    __shared__ int lc[NBUCK];
    __shared__ int lb[NBUCK];
    int t = threadIdx.x;
    for (int b = t; b < NBUCK; b += 256) lc[b] = 0;
    __syncthreads();
    int base = blockIdx.x * CHUNK;
    int pk[16], bk[16], rk[16];
#pragma unroll
    for (int i = 0; i < 16; ++i) {
        int e = base + i * 256 + t;
        rk[i] = -1;
        if (e < N_EDGES) {
            int s = src[e], d = dst[e];
            bk[i] = d >> BSHIFT;
            pk[i] = (s << BSHIFT) | (d & 255);
            rk[i] = atomicAdd(&lc[bk[i]], 1);
        }
    }
    __syncthreads();
    for (int b = t; b < NBUCK; b += 256)
        lb[b] = lc[b] ? atomicAdd(&bfill[b], lc[b]) : 0;
    __syncthreads();
#pragma unroll
    for (int i = 0; i < 16; ++i)
        if (rk[i] >= 0) ebuck[lb[bk[i]] + rk[i]] = pk[i];
}

__global__ __launch_bounds__(256) void k_deg(const int* __restrict__ bstart,
                                             const int* __restrict__ ebuck,
                                             int* __restrict__ deg) {
    __shared__ int ld[256];
    int b = blockIdx.x, t = threadIdx.x;
    ld[t] = 1;  // self loop
    __syncthreads();
    int s = bstart[b], e = bstart[b + 1];
    for (int j = s + t; j < e; j += 256) atomicAdd(&ld[ebuck[j] & 255], 1);
    __syncthreads();
    int node = (b << BSHIFT) + t;
    if (node < N_NODES) deg[node] = ld[t];
}

// ---------------- rowptr scan ----------------

__global__ void k_scan1(const int* __restrict__ deg, float* __restrict__ dinv,
                        int* __restrict__ bsum) {
    __shared__ int s[256];
    int t = threadIdx.x;
    int i = blockIdx.x * 256 + t;
    int c = 0;
    if (i < N_NODES) {
        int d = deg[i];
        dinv[i] = rsqrtf((float)d);
        c = d - 1;
    }
    s[t] = c; __syncthreads();
    for (int off = 128; off; off >>= 1) {
        if (t < off) s[t] += s[t + off];
        __syncthreads();
    }
    if (t == 0) bsum[blockIdx.x] = s[0];
}

__global__ void k_scan2(const int* __restrict__ bsum, int* __restrict__ bscan, int nb) {
    __shared__ int s[512];
    int t = threadIdx.x;
    int v = (t < nb) ? bsum[t] : 0;
    s[t] = v; __syncthreads();
    for (int off = 1; off < 512; off <<= 1) {
        int u = 0;
        if (t >= off) u = s[t - off];
        __syncthreads();
        s[t] += u;
        __syncthreads();
    }
    if (t < nb) bscan[t] = s[t] - v;
}

__global__ void k_scan3(const int* __restrict__ deg, const int* __restrict__ bscan,
                        int* __restrict__ rowptr) {
    __shared__ int s[256];
    int t = threadIdx.x;
    int i = blockIdx.x * 256 + t;
    int c = (i < N_NODES) ? deg[i] - 1 : 0;
    s[t] = c; __syncthreads();
    for (int off = 1; off < 256; off <<= 1) {
        int u = 0;
        if (t >= off) u = s[t - off];
        __syncthreads();
        s[t] += u;
        __syncthreads();
    }
    if (i < N_NODES) rowptr[i] = bscan[blockIdx.x] + s[t] - c;  // exclusive
}

// CSR fill: col only (weights folded into dinv-prescaled T)
__global__ __launch_bounds__(256) void k_fill(const int* __restrict__ bstart,
                                              const int* __restrict__ ebuck,
                                              const int* __restrict__ rowptr,
                                              int* __restrict__ col) {
    __shared__ int lf[256];
    int b = blockIdx.x, t = threadIdx.x;
    int node = (b << BSHIFT) + t;
    lf[t] = (node < N_NODES) ? rowptr[node] : 0;
    __syncthreads();
    int s = bstart[b], e = bstart[b + 1];
    for (int j = s + t; j < e; j += 256) {
        int v = ebuck[j];
        int pos = atomicAdd(&lf[v & 255], 1);
        col[pos] = v >> BSHIFT;
    }
}

// ---------------- MFMA GEMMs: Tb[N,64](bf16) = dinv[row] * (Xin @ W) ----------------
// 16x16x32 bf16 MFMA. Verified layouts: A[m=lane&15][k=(lane>>4)*8+j],
// B[n=lane&15][k=(lane>>4)*8+j] (from W transposed in LDS), D[row=(lane>>4)*4+r][col=lane&15].
// Block = 256 thr = 4 waves; tile 128 rows x 64 cols; wave w owns rows w*32..w*32+31.

// GEMM1: fp32 X [N,256], converts to bf16 during staging.
__global__ __launch_bounds__(256) void k_gemm1(const float* __restrict__ X,
                                               const float* __restrict__ W,
                                               const float* __restrict__ dinv,
                                               unsigned short* __restrict__ Tb) {
    __shared__ unsigned short Xb[128][72];    // 18.4 KB (stride 72: 16B-aligned b128 reads)
    __shared__ unsigned short Wt[64][264];    // 33.8 KB, W transposed, full K=256
    const int t = threadIdx.x;
    const int lane = t & 63, wv = t >> 6;
    const int fl = lane & 15, quad = lane >> 4;
    const int r0 = blockIdx.x * 128;

    // stage Wt (transposed, bf16) once
    for (int j = t; j < IN_DIM * HID; j += 256) {
        int k = j >> 6, c = j & 63;
        Wt[c][k] = f2b(W[j]);
    }

    floatx4 acc[2][4];
#pragma unroll
    for (int i = 0; i < 2; ++i)
#pragma unroll
        for (int j = 0; j < 4; ++j) acc[i][j] = (floatx4){0.f, 0.f, 0.f, 0.f};

    for (int k0 = 0; k0 < IN_DIM; k0 += 64) {
        // stage Xb: 128 rows x 64 k fp32 -> bf16; 2048 float4 / 256 thr = 8 each
#pragma unroll
        for (int s = 0; s < 8; ++s) {
            int j = t + 256 * s;
            int row = j >> 4, f4 = j & 15;
            float4 v = make_float4(0.f, 0.f, 0.f, 0.f);
            if (r0 + row < N_NODES)
                v = *(const float4*)(X + (size_t)(r0 + row) * IN_DIM + k0 + f4 * 4);
            ushort4 o;
            o.x = f2b(v.x); o.y = f2b(v.y); o.z = f2b(v.z); o.w = f2b(v.w);
            *(ushort4*)&Xb[row][f4 * 4] = o;
        }
        __syncthreads();
#pragma unroll
        for (int kc = 0; kc < 64; kc += 32) {
            short8 a0 = *(const short8*)&Xb[wv * 32 + fl][kc + quad * 8];
            short8 a1 = *(const short8*)&Xb[wv * 32 + 16 + fl][kc + quad * 8];
#pragma unroll
            for (int ct = 0; ct < 4; ++ct) {
                short8 b = *(const short8*)&Wt[ct * 16 + fl][k0 + kc + quad * 8];
                acc[0][ct] = __builtin_amdgcn_mfma_f32_16x16x32_bf16(a0, b, acc[0][ct], 0, 0, 0);
                acc[1][ct] = __builtin_amdgcn_mfma_f32_16x16x32_bf16(a1, b, acc[1][ct], 0, 0, 0);
            }
        }
        __syncthreads();
    }

#pragma unroll
    for (int rt = 0; rt < 2; ++rt) {
        int rbase = r0 + wv * 32 + rt * 16 + quad * 4;
#pragma unroll
        for (int r = 0; r < 4; ++r) {
            int row = rbase + r;
            if (row < N_NODES) {
                float di = dinv[row];
#pragma unroll
                for (int ct = 0; ct < 4; ++ct)
                    Tb[(size_t)row * HID + ct * 16 + fl] = f2b(di * acc[rt][ct][r]);
            }
        }
    }
}

// GEMM2/3: bf16 input H [N,64]
__global__ __launch_bounds__(256) void k_gemm2(const unsigned short* __restrict__ Xin,
                                               const float* __restrict__ W,
                                               const float* __restrict__ dinv,
                                               unsigned short* __restrict__ Tb) {
    __shared__ unsigned short Xb[128][72];
    __shared__ unsigned short Wt[64][72];
    const int t = threadIdx.x;
    const int lane = t & 63, wv = t >> 6;
    const int fl = lane & 15, quad = lane >> 4;
    const int r0 = blockIdx.x * 128;

    for (int j = t; j < HID * HID; j += 256) {
        int k = j >> 6, c = j & 63;
        Wt[c][k] = f2b(W[j]);
    }
    // stage Xb: 128 rows x 64 bf16 = 1024 us8 chunks / 256 thr = 4 each
#pragma unroll
    for (int s = 0; s < 4; ++s) {
        int j = t + 256 * s;
        int row = j >> 3, c8 = j & 7;
        us8 v = (us8){0, 0, 0, 0, 0, 0, 0, 0};
        if (r0 + row < N_NODES)
            v = *(const us8*)(Xin + (size_t)(r0 + row) * HID + c8 * 8);
        *(us8*)&Xb[row][c8 * 8] = v;
    }
    __syncthreads();

    floatx4 acc[2][4];
#pragma unroll
    for (int i = 0; i < 2; ++i)
#pragma unroll
        for (int j = 0; j < 4; ++j) acc[i][j] = (floatx4){0.f, 0.f, 0.f, 0.f};

#pragma unroll
    for (int kc = 0; kc < 64; kc += 32) {
        short8 a0 = *(const short8*)&Xb[wv * 32 + fl][kc + quad * 8];
        short8 a1 = *(const short8*)&Xb[wv * 32 + 16 + fl][kc + quad * 8];
#pragma unroll
        for (int ct = 0; ct < 4; ++ct) {
            short8 b = *(const short8*)&Wt[ct * 16 + fl][kc + quad * 8];
            acc[0][ct] = __builtin_amdgcn_mfma_f32_16x16x32_bf16(a0, b, acc[0][ct], 0, 0, 0);
            acc[1][ct] = __builtin_amdgcn_mfma_f32_16x16x32_bf16(a1, b, acc[1][ct], 0, 0, 0);
        }
    }

#pragma unroll
    for (int rt = 0; rt < 2; ++rt) {
        int rbase = r0 + wv * 32 + rt * 16 + quad * 4;
#pragma unroll
        for (int r = 0; r < 4; ++r) {
            int row = rbase + r;
            if (row < N_NODES) {
                float di = dinv[row];
#pragma unroll
                for (int ct = 0; ct < 4; ++ct)
                    Tb[(size_t)row * HID + ct * 16 + fl] = f2b(di * acc[rt][ct][r]);
            }
        }
    }
}

// ---------------- aggregation: H[i] = relu(dinv[i]*(Tb[i] + sum_e Tb[src]) + b) ----------------
// Wave per node. grp=lane>>4 covers 4 edges/instr, fl=lane&15 covers 4 features (ushort4).
// Gather instr = 64 lanes x 8 B = 512 B spanning 4 edge rows.

__global__ __launch_bounds__(256) void k_agg(const unsigned short* __restrict__ Tb,
                                             const int* __restrict__ rowptr,
                                             const int* __restrict__ deg,
                                             const float* __restrict__ dinv,
                                             const int* __restrict__ col,
                                             const float* __restrict__ bias,
                                             unsigned short* __restrict__ Hb) {
    int lane = threadIdx.x & 63;
    int node = blockIdx.x * 4 + (threadIdx.x >> 6);
    int grp = lane >> 4, fl = lane & 15;
    int e = __builtin_amdgcn_readfirstlane(rowptr[node]);
    int end = e + __builtin_amdgcn_readfirstlane(deg[node]) - 1;
    float ax = 0.f, ay = 0.f, az = 0.f, aw = 0.f;
    float bx = 0.f, by = 0.f, bz = 0.f, bw = 0.f;
    for (; e + 8 <= end; e += 8) {
        int s0 = col[e + grp];
        int s1 = col[e + 4 + grp];
        ushort4 t0 = *(const ushort4*)(Tb + (size_t)s0 * HID + fl * 4);
        ushort4 t1 = *(const ushort4*)(Tb + (size_t)s1 * HID + fl * 4);
        ax += b2f(t0.x); ay += b2f(t0.y); az += b2f(t0.z); aw += b2f(t0.w);
        bx += b2f(t1.x); by += b2f(t1.y); bz += b2f(t1.z); bw += b2f(t1.w);
    }
    for (; e < end; e += 4) {
        int idx = e + grp;
        if (idx < end) {
            int s = col[idx];
            ushort4 tv = *(const ushort4*)(Tb + (size_t)s * HID + fl * 4);
            ax += b2f(tv.x); ay += b2f(tv.y); az += b2f(tv.z); aw += b2f(tv.w);
        }
    }
    ax += bx; ay += by; az += bz; aw += bw;
    ax += __shfl_xor(ax, 16); ay += __shfl_xor(ay, 16);
    az += __shfl_xor(az, 16); aw += __shfl_xor(aw, 16);
    ax += __shfl_xor(ax, 32); ay += __shfl_xor(ay, 32);
    az += __shfl_xor(az, 32); aw += __shfl_xor(aw, 32);
    // self row (Tb already dinv-prescaled)
    ushort4 sv = *(const ushort4*)(Tb + (size_t)node * HID + fl * 4);
    ax += b2f(sv.x); ay += b2f(sv.y); az += b2f(sv.z); aw += b2f(sv.w);
    float di = dinv[node];
    float4 bs = *(const float4*)(bias + fl * 4);
    ax = fmaxf(fmaf(di, ax, bs.x), 0.f);
    ay = fmaxf(fmaf(di, ay, bs.y), 0.f);
    az = fmaxf(fmaf(di, az, bs.z), 0.f);
    aw = fmaxf(fmaf(di, aw, bs.w), 0.f);
    if (grp == 0) {
        ushort4 o;
        o.x = f2b(ax); o.y = f2b(ay); o.z = f2b(az); o.w = f2b(aw);
        *(ushort4*)(Hb + (size_t)node * HID + fl * 4) = o;
    }
}

// layer-3 aggregation (no relu) fused with pooling + final linear
__global__ __launch_bounds__(256) void k_agg_pool(const unsigned short* __restrict__ Tb,
                                                  const int* __restrict__ rowptr,
                                                  const int* __restrict__ deg,
                                                  const float* __restrict__ dinv,
                                                  const int* __restrict__ col,
                                                  const float* __restrict__ bias,
                                                  const float* __restrict__ Wl,
                                                  const int* __restrict__ batch,
                                                  float* __restrict__ partial) {
    int lane = threadIdx.x & 63;
    int node = blockIdx.x * 4 + (threadIdx.x >> 6);
    int grp = lane >> 4, fl = lane & 15;
    int e = __builtin_amdgcn_readfirstlane(rowptr[node]);
    int end = e + __builtin_amdgcn_readfirstlane(deg[node]) - 1;
    float ax = 0.f, ay = 0.f, az = 0.f, aw = 0.f;
    float bx = 0.f, by = 0.f, bz = 0.f, bw = 0.f;
    for (; e + 8 <= end; e += 8) {
        int s0 = col[e + grp];
        int s1 = col[e + 4 + grp];
        ushort4 t0 = *(const ushort4*)(Tb + (size_t)s0 * HID + fl * 4);
        ushort4 t1 = *(const ushort4*)(Tb + (size_t)s1 * HID + fl * 4);
        ax += b2f(t0.x); ay += b2f(t0.y); az += b2f(t0.z); aw += b2f(t0.w);
        bx += b2f(t1.x); by += b2f(t1.y); bz += b2f(t1.z); bw += b2f(t1.w);
    }
    for (; e < end; e += 4) {
        int idx = e + grp;
        if (idx < end) {
            int s = col[idx];
            ushort4 tv = *(const ushort4*)(Tb + (size_t)s * HID + fl * 4);
            ax += b2f(tv.x); ay += b2f(tv.y); az += b2f(tv.z); aw += b2f(tv.w);
        }
    }
    ax += bx; ay += by; az += bz; aw += bw;
    ax += __shfl_xor(ax, 16); ay += __shfl_xor(ay, 16);
    az += __shfl_xor(az, 16); aw += __shfl_xor(aw, 16);
    ax += __shfl_xor(ax, 32); ay += __shfl_xor(ay, 32);
    az += __shfl_xor(az, 32); aw += __shfl_xor(aw, 32);
    ushort4 sv = *(const ushort4*)(Tb + (size_t)node * HID + fl * 4);
    ax += b2f(sv.x); ay += b2f(sv.y); az += b2f(sv.z); aw += b2f(sv.w);
    float di = dinv[node];
    float4 bs = *(const float4*)(bias + fl * 4);
    ax = fmaf(di, ax, bs.x);
    ay = fmaf(di, ay, bs.y);
    az = fmaf(di, az, bs.z);
    aw = fmaf(di, aw, bs.w);
    float4 wl = *(const float4*)(Wl + fl * 4);
    float s = ax * wl.x + ay * wl.y + az * wl.z + aw * wl.w;
    s += __shfl_xor(s, 1);
    s += __shfl_xor(s, 2);
    s += __shfl_xor(s, 4);
    s += __shfl_xor(s, 8);
    if (lane == 0)
        atomicAdd(&partial[(blockIdx.x & (NPART - 1)) * PSTRIDE + batch[node]], s);
}

__global__ void k_pool_reduce(const float* __restrict__ partial,
                              const float* __restrict__ bl,
                              float* __restrict__ out) {
    int g = threadIdx.x;
    if (g >= N_GRAPHS) return;
    float s = bl[0];
    for (int p = 0; p < NPART; ++p) s += partial[p * PSTRIDE + g];
    out[g] = s;
}

extern "C" void kernel_launch(void* const* d_in, const int* in_sizes, int n_in,
                              void* d_out, int out_size, void* d_ws, size_t ws_size,
                              hipStream_t stream) {
    const float* x     = (const float*)d_in[0];
    const int*   ei    = (const int*)d_in[1];
    const int*   batch = (const int*)d_in[2];
    const float* W1    = (const float*)d_in[3];
    const float* b1    = (const float*)d_in[4];
    const float* W2    = (const float*)d_in[5];
    const float* b2    = (const float*)d_in[6];
    const float* W3    = (const float*)d_in[7];
    const float* b3    = (const float*)d_in[8];
    const float* Wl    = (const float*)d_in[9];
    const float* bl    = (const float*)d_in[10];
    float* out = (float*)d_out;

    char* p = (char*)d_ws;
    unsigned short* tb = (unsigned short*)p; p += (size_t)N_NODES * HID * 2;  // 12.8 MB
    unsigned short* hB = (unsigned short*)p; p += (size_t)N_NODES * HID * 2;  // 12.8 MB
    int*   col     = (int*)p;   p += (size_t)(N_EDGES + 16) * 4;              // 6.4 MB
    int*   ebuck   = (int*)p;   p += (size_t)N_EDGES * 4;                     // 6.4 MB
    int*   deg     = (int*)p;   p += (size_t)N_NODES * 4;
    float* dinv    = (float*)p; p += (size_t)N_NODES * 4;
    int*   rowptr  = (int*)p;   p += (size_t)N_NODES * 4;
    int*   bcount  = (int*)p;   p += (NBUCK + 1) * 4;
    int*   bstart  = (int*)p;   p += (NBUCK + 1) * 4;
    int*   bfill   = (int*)p;   p += (NBUCK + 1) * 4;
    int*   bsum    = (int*)p;   p += 512 * 4;
    int*   bscan   = (int*)p;   p += 512 * 4;
    float* partial = (float*)p; p += (size_t)NPART * PSTRIDE * 4;

    const int* src  = ei;
    const int* dstp = ei + N_EDGES;

    const int nb = (N_NODES + 255) / 256;            // 391
    const int cb = (N_EDGES + CHUNK - 1) / CHUNK;    // 391
    const int gemm_blocks = (N_NODES + 127) / 128;   // 782
    const int node_wave_blocks = (N_NODES + 3) / 4;  // 25000

    k_zero_misc<<<(NPART * PSTRIDE + 255) / 256, 256, 0, stream>>>(bcount, partial);
    k_bhist<<<cb, 256, 0, stream>>>(dstp, bcount);
    k_bscan<<<1, 512, 0, stream>>>(bcount, bstart, bfill);
    k_bscatter<<<cb, 256, 0, stream>>>(src, dstp, bfill, ebuck);
    k_deg<<<NBUCK, 256, 0, stream>>>(bstart, ebuck, deg);
    k_scan1<<<nb, 256, 0, stream>>>(deg, dinv, bsum);
    k_scan2<<<1, 512, 0, stream>>>(bsum, bscan, nb);
    k_scan3<<<nb, 256, 0, stream>>>(deg, bscan, rowptr);
    k_fill<<<NBUCK, 256, 0, stream>>>(bstart, ebuck, rowptr, col);

    k_gemm1<<<gemm_blocks, 256, 0, stream>>>(x, W1, dinv, tb);
    k_agg<<<node_wave_blocks, 256, 0, stream>>>(tb, rowptr, deg, dinv, col, b1, hB);
    k_gemm2<<<gemm_blocks, 256, 0, stream>>>(hB, W2, dinv, tb);
    k_agg<<<node_wave_blocks, 256, 0, stream>>>(tb, rowptr, deg, dinv, col, b2, hB);
    k_gemm2<<<gemm_blocks, 256, 0, stream>>>(hB, W3, dinv, tb);
    k_agg_pool<<<node_wave_blocks, 256, 0, stream>>>(tb, rowptr, deg, dinv, col, b3,
                                                     Wl, batch, partial);

    k_pool_reduce<<<1, 128, 0, stream>>>(partial, bl, out);
}

// Round 8
// 431.439 us; speedup vs baseline: 3.9618x; 1.0454x over previous
//
#include <hip/hip_runtime.h>

#define N_NODES 100000
#define N_EDGES 1600000
#define IN_DIM 256
#define HID 64
#define N_GRAPHS 100
#define NPART 256
#define PSTRIDE 128
#define BSHIFT 8
#define NBUCK 391   // ceil(N_NODES / 256)
#define CHUNK 4096  // edges per block in bucket passes

typedef __attribute__((ext_vector_type(8))) short short8;
typedef __attribute__((ext_vector_type(8))) unsigned short us8;
typedef __attribute__((ext_vector_type(4))) float floatx4;

// bf16 helpers (RNE)
__device__ __forceinline__ unsigned short f2b(float f) {
    unsigned int u = __float_as_uint(f);
    unsigned int r = (u + 0x7FFFu + ((u >> 16) & 1u)) >> 16;
    return (unsigned short)r;
}
__device__ __forceinline__ float b2f(unsigned short b) {
    return __uint_as_float(((unsigned int)b) << 16);
}

// ---------------- W prep: transpose + bf16 once ----------------

__global__ void k_wprep(const float* __restrict__ W1, const float* __restrict__ W2,
                        const float* __restrict__ W3,
                        unsigned short* __restrict__ wt1, unsigned short* __restrict__ wt2,
                        unsigned short* __restrict__ wt3) {
    int i = blockIdx.x * 256 + threadIdx.x;
    if (i < IN_DIM * HID) {
        int k = i >> 6, n = i & 63;
        wt1[n * IN_DIM + k] = f2b(W1[i]);
    }
    if (i < HID * HID) {
        int k = i >> 6, n = i & 63;
        wt2[n * HID + k] = f2b(W2[i]);
        wt3[n * HID + k] = f2b(W3[i]);
    }
}

// ---------------- bucketed edge partition ----------------

__global__ void k_zero_misc(int* __restrict__ bcount, float* __restrict__ partial) {
    int i = blockIdx.x * 256 + threadIdx.x;
    if (i < NBUCK) bcount[i] = 0;
    if (i < NPART * PSTRIDE) partial[i] = 0.f;
}

__global__ __launch_bounds__(256) void k_bhist(const int* __restrict__ dst,
                                               int* __restrict__ bcount) {
    __shared__ int lc[NBUCK];
    int t = threadIdx.x;
    for (int b = t; b < NBUCK; b += 256) lc[b] = 0;
    __syncthreads();
    int base = blockIdx.x * CHUNK;
#pragma unroll
    for (int i = 0; i < 16; ++i) {
        int e = base + i * 256 + t;
        if (e < N_EDGES) atomicAdd(&lc[dst[e] >> BSHIFT], 1);
    }
    __syncthreads();
    for (int b = t; b < NBUCK; b += 256)
        if (lc[b]) atomicAdd(&bcount[b], lc[b]);
}

__global__ void k_bscan(const int* __restrict__ bcount, int* __restrict__ bstart,
                        int* __restrict__ bfill) {
    __shared__ int s[512];
    int t = threadIdx.x;
    int v = (t < NBUCK) ? bcount[t] : 0;
    s[t] = v; __syncthreads();
    for (int off = 1; off < 512; off <<= 1) {
        int u = 0;
        if (t >= off) u = s[t - off];
        __syncthreads();
        s[t] += u;
        __syncthreads();
    }
    if (t < NBUCK) { int st = s[t] - v; bstart[t] = st; bfill[t] = st; }
    if (t == 0) bstart[NBUCK] = N_EDGES;
}

__global__ __launch_bounds__(256) void k_bscatter(const int* __restrict__ src,
                                                  const int* __restrict__ dst,
                                                  int* __restrict__ bfill,
                                                  int* __restrict__ ebuck) {
    __shared__ int lc[NBUCK];
    __shared__ int lb[NBUCK];
    int t = threadIdx.x;
    for (int b = t; b < NBUCK; b += 256) lc[b] = 0;
    __syncthreads();
    int base = blockIdx.x * CHUNK;
    int pk[16], bk[16], rk[16];
#pragma unroll
    for (int i = 0; i < 16; ++i) {
        int e = base + i * 256 + t;
        rk[i] = -1;
        if (e < N_EDGES) {
            int s = src[e], d = dst[e];
            bk[i] = d >> BSHIFT;
            pk[i] = (s << BSHIFT) | (d & 255);
            rk[i] = atomicAdd(&lc[bk[i]], 1);
        }
    }
    __syncthreads();
    for (int b = t; b < NBUCK; b += 256)
        lb[b] = lc[b] ? atomicAdd(&bfill[b], lc[b]) : 0;
    __syncthreads();
#pragma unroll
    for (int i = 0; i < 16; ++i)
        if (rk[i] >= 0) ebuck[lb[bk[i]] + rk[i]] = pk[i];
}

__global__ __launch_bounds__(256) void k_deg(const int* __restrict__ bstart,
                                             const int* __restrict__ ebuck,
                                             int* __restrict__ deg) {
    __shared__ int ld[256];
    int b = blockIdx.x, t = threadIdx.x;
    ld[t] = 1;  // self loop
    __syncthreads();
    int s = bstart[b], e = bstart[b + 1];
    for (int j = s + t; j < e; j += 256) atomicAdd(&ld[ebuck[j] & 255], 1);
    __syncthreads();
    int node = (b << BSHIFT) + t;
    if (node < N_NODES) deg[node] = ld[t];
}

// ---------------- rowptr scan ----------------

__global__ void k_scan1(const int* __restrict__ deg, float* __restrict__ dinv,
                        int* __restrict__ bsum) {
    __shared__ int s[256];
    int t = threadIdx.x;
    int i = blockIdx.x * 256 + t;
    int c = 0;
    if (i < N_NODES) {
        int d = deg[i];
        dinv[i] = rsqrtf((float)d);
        c = d - 1;
    }
    s[t] = c; __syncthreads();
    for (int off = 128; off; off >>= 1) {
        if (t < off) s[t] += s[t + off];
        __syncthreads();
    }
    if (t == 0) bsum[blockIdx.x] = s[0];
}

__global__ void k_scan2(const int* __restrict__ bsum, int* __restrict__ bscan, int nb) {
    __shared__ int s[512];
    int t = threadIdx.x;
    int v = (t < nb) ? bsum[t] : 0;
    s[t] = v; __syncthreads();
    for (int off = 1; off < 512; off <<= 1) {
        int u = 0;
        if (t >= off) u = s[t - off];
        __syncthreads();
        s[t] += u;
        __syncthreads();
    }
    if (t < nb) bscan[t] = s[t] - v;
}

__global__ void k_scan3(const int* __restrict__ deg, const int* __restrict__ bscan,
                        int* __restrict__ rowptr) {
    __shared__ int s[256];
    int t = threadIdx.x;
    int i = blockIdx.x * 256 + t;
    int c = (i < N_NODES) ? deg[i] - 1 : 0;
    s[t] = c; __syncthreads();
    for (int off = 1; off < 256; off <<= 1) {
        int u = 0;
        if (t >= off) u = s[t - off];
        __syncthreads();
        s[t] += u;
        __syncthreads();
    }
    if (i < N_NODES) rowptr[i] = bscan[blockIdx.x] + s[t] - c;  // exclusive
}

// CSR fill: col only (weights folded into dinv-prescaled T)
__global__ __launch_bounds__(256) void k_fill(const int* __restrict__ bstart,
                                              const int* __restrict__ ebuck,
                                              const int* __restrict__ rowptr,
                                              int* __restrict__ col) {
    __shared__ int lf[256];
    int b = blockIdx.x, t = threadIdx.x;
    int node = (b << BSHIFT) + t;
    lf[t] = (node < N_NODES) ? rowptr[node] : 0;
    __syncthreads();
    int s = bstart[b], e = bstart[b + 1];
    for (int j = s + t; j < e; j += 256) {
        int v = ebuck[j];
        int pos = atomicAdd(&lf[v & 255], 1);
        col[pos] = v >> BSHIFT;
    }
}

// ---------------- MFMA GEMM1: Tb = dinv * (X[fp32] @ W1), double-buffered ----------------
// 64-row tile, 1563 blocks, 4 k-tiles of 64. One barrier/tile; next tile's global
// loads issued before the barrier so they overlap compute (duty-cycle fix).

__global__ __launch_bounds__(256) void k_gemm1(const float* __restrict__ X,
                                               const unsigned short* __restrict__ Wt,
                                               const float* __restrict__ dinv,
                                               unsigned short* __restrict__ Tb) {
    __shared__ unsigned short Xb[2][64][72];   // 18.4 KB
    __shared__ unsigned short Wb[2][64][72];   // 18.4 KB
    const int t = threadIdx.x;
    const int lane = t & 63, wv = t >> 6;
    const int fl = lane & 15, quad = lane >> 4;
    const int r0 = blockIdx.x * 64;
    const int xrow = t >> 4, xf4 = t & 15;   // X stage: 16 thr/row, rows xrow+16s
    const int wn = t >> 3, wc8 = t & 7;      // W stage: 8 thr/row, rows wn+32s

    float4 xv[4];
    us8 wreg[2];

#pragma unroll
    for (int s = 0; s < 4; ++s) {
        int row = xrow + s * 16;
        xv[s] = (r0 + row < N_NODES)
                    ? *(const float4*)(X + (size_t)(r0 + row) * IN_DIM + xf4 * 4)
                    : make_float4(0.f, 0.f, 0.f, 0.f);
    }
#pragma unroll
    for (int s = 0; s < 2; ++s)
        wreg[s] = *(const us8*)(Wt + (wn + s * 32) * IN_DIM + wc8 * 8);

    floatx4 acc[4];
#pragma unroll
    for (int j = 0; j < 4; ++j) acc[j] = (floatx4){0.f, 0.f, 0.f, 0.f};

    int pb = 0;
#pragma unroll
    for (int tt = 0; tt < 4; ++tt) {
#pragma unroll
        for (int s = 0; s < 4; ++s) {
            int row = xrow + s * 16;
            ushort4 o;
            o.x = f2b(xv[s].x); o.y = f2b(xv[s].y);
            o.z = f2b(xv[s].z); o.w = f2b(xv[s].w);
            *(ushort4*)&Xb[pb][row][xf4 * 4] = o;
        }
#pragma unroll
        for (int s = 0; s < 2; ++s)
            *(us8*)&Wb[pb][wn + s * 32][wc8 * 8] = wreg[s];
        if (tt < 3) {
            int k0 = (tt + 1) * 64;
#pragma unroll
            for (int s = 0; s < 4; ++s) {
                int row = xrow + s * 16;
                xv[s] = (r0 + row < N_NODES)
                            ? *(const float4*)(X + (size_t)(r0 + row) * IN_DIM + k0 + xf4 * 4)
                            : make_float4(0.f, 0.f, 0.f, 0.f);
            }
#pragma unroll
            for (int s = 0; s < 2; ++s)
                wreg[s] = *(const us8*)(Wt + (wn + s * 32) * IN_DIM + k0 + wc8 * 8);
        }
        __syncthreads();
#pragma unroll
        for (int kc = 0; kc < 64; kc += 32) {
            short8 a = *(const short8*)&Xb[pb][wv * 16 + fl][kc + quad * 8];
#pragma unroll
            for (int ct = 0; ct < 4; ++ct) {
                short8 b = *(const short8*)&Wb[pb][ct * 16 + fl][kc + quad * 8];
                acc[ct] = __builtin_amdgcn_mfma_f32_16x16x32_bf16(a, b, acc[ct], 0, 0, 0);
            }
        }
        pb ^= 1;
    }

    int rbase = r0 + wv * 16 + quad * 4;
#pragma unroll
    for (int r = 0; r < 4; ++r) {
        int row = rbase + r;
        if (row < N_NODES) {
            float di = dinv[row];
#pragma unroll
            for (int ct = 0; ct < 4; ++ct)
                Tb[(size_t)row * HID + ct * 16 + fl] = f2b(di * acc[ct][r]);
        }
    }
}

// ---------------- MFMA GEMM2/3: Tb = dinv * (Hb[bf16] @ W), single k-tile ----------------
// 64-row tile, 18.4 KB LDS -> 8 blocks/CU.

__global__ __launch_bounds__(256) void k_gemm2(const unsigned short* __restrict__ Xin,
                                               const unsigned short* __restrict__ Wt,
                                               const float* __restrict__ dinv,
                                               unsigned short* __restrict__ Tb) {
    __shared__ unsigned short Xb[64][72];
    __shared__ unsigned short Wb[64][72];
    const int t = threadIdx.x;
    const int lane = t & 63, wv = t >> 6;
    const int fl = lane & 15, quad = lane >> 4;
    const int r0 = blockIdx.x * 64;
    const int xr = t >> 3, c8 = t & 7;

#pragma unroll
    for (int s = 0; s < 2; ++s) {
        int row = xr + s * 32;
        us8 v = (r0 + row < N_NODES)
                    ? *(const us8*)(Xin + (size_t)(r0 + row) * HID + c8 * 8)
                    : (us8){0, 0, 0, 0, 0, 0, 0, 0};
        *(us8*)&Xb[row][c8 * 8] = v;
        *(us8*)&Wb[row][c8 * 8] = *(const us8*)(Wt + row * HID + c8 * 8);
    }
    __syncthreads();

    floatx4 acc[4];
#pragma unroll
    for (int j = 0; j < 4; ++j) acc[j] = (floatx4){0.f, 0.f, 0.f, 0.f};
#pragma unroll
    for (int kc = 0; kc < 64; kc += 32) {
        short8 a = *(const short8*)&Xb[wv * 16 + fl][kc + quad * 8];
#pragma unroll
        for (int ct = 0; ct < 4; ++ct) {
            short8 b = *(const short8*)&Wb[ct * 16 + fl][kc + quad * 8];
            acc[ct] = __builtin_amdgcn_mfma_f32_16x16x32_bf16(a, b, acc[ct], 0, 0, 0);
        }
    }

    int rbase = r0 + wv * 16 + quad * 4;
#pragma unroll
    for (int r = 0; r < 4; ++r) {
        int row = rbase + r;
        if (row < N_NODES) {
            float di = dinv[row];
#pragma unroll
            for (int ct = 0; ct < 4; ++ct)
                Tb[(size_t)row * HID + ct * 16 + fl] = f2b(di * acc[ct][r]);
        }
    }
}

// ---------------- aggregation: H[i] = relu(dinv[i]*(Tb[i] + sum_e Tb[src]) + b) ----------------

__global__ __launch_bounds__(256) void k_agg(const unsigned short* __restrict__ Tb,
                                             const int* __restrict__ rowptr,
                                             const int* __restrict__ deg,
                                             const float* __restrict__ dinv,
                                             const int* __restrict__ col,
                                             const float* __restrict__ bias,
                                             unsigned short* __restrict__ Hb) {
    int lane = threadIdx.x & 63;
    int node = blockIdx.x * 4 + (threadIdx.x >> 6);
    int grp = lane >> 4, fl = lane & 15;
    int e = __builtin_amdgcn_readfirstlane(rowptr[node]);
    int end = e + __builtin_amdgcn_readfirstlane(deg[node]) - 1;
    float ax = 0.f, ay = 0.f, az = 0.f, aw = 0.f;
    float bx = 0.f, by = 0.f, bz = 0.f, bw = 0.f;
    for (; e + 8 <= end; e += 8) {
        int s0 = col[e + grp];
        int s1 = col[e + 4 + grp];
        ushort4 t0 = *(const ushort4*)(Tb + (size_t)s0 * HID + fl * 4);
        ushort4 t1 = *(const ushort4*)(Tb + (size_t)s1 * HID + fl * 4);
        ax += b2f(t0.x); ay += b2f(t0.y); az += b2f(t0.z); aw += b2f(t0.w);
        bx += b2f(t1.x); by += b2f(t1.y); bz += b2f(t1.z); bw += b2f(t1.w);
    }
    for (; e < end; e += 4) {
        int idx = e + grp;
        if (idx < end) {
            int s = col[idx];
            ushort4 tv = *(const ushort4*)(Tb + (size_t)s * HID + fl * 4);
            ax += b2f(tv.x); ay += b2f(tv.y); az += b2f(tv.z); aw += b2f(tv.w);
        }
    }
    ax += bx; ay += by; az += bz; aw += bw;
    ax += __shfl_xor(ax, 16); ay += __shfl_xor(ay, 16);
    az += __shfl_xor(az, 16); aw += __shfl_xor(aw, 16);
    ax += __shfl_xor(ax, 32); ay += __shfl_xor(ay, 32);
    az += __shfl_xor(az, 32); aw += __shfl_xor(aw, 32);
    ushort4 sv = *(const ushort4*)(Tb + (size_t)node * HID + fl * 4);
    ax += b2f(sv.x); ay += b2f(sv.y); az += b2f(sv.z); aw += b2f(sv.w);
    float di = dinv[node];
    float4 bs = *(const float4*)(bias + fl * 4);
    ax = fmaxf(fmaf(di, ax, bs.x), 0.f);
    ay = fmaxf(fmaf(di, ay, bs.y), 0.f);
    az = fmaxf(fmaf(di, az, bs.z), 0.f);
    aw = fmaxf(fmaf(di, aw, bs.w), 0.f);
    if (grp == 0) {
        ushort4 o;
        o.x = f2b(ax); o.y = f2b(ay); o.z = f2b(az); o.w = f2b(aw);
        *(ushort4*)(Hb + (size_t)node * HID + fl * 4) = o;
    }
}

__global__ __launch_bounds__(256) void k_agg_pool(const unsigned short* __restrict__ Tb,
                                                  const int* __restrict__ rowptr,
                                                  const int* __restrict__ deg,
                                                  const float* __restrict__ dinv,
                                                  const int* __restrict__ col,
                                                  const float* __restrict__ bias,
                                                  const float* __restrict__ Wl,
                                                  const int* __restrict__ batch,
                                                  float* __restrict__ partial) {
    int lane = threadIdx.x & 63;
    int node = blockIdx.x * 4 + (threadIdx.x >> 6);
    int grp = lane >> 4, fl = lane & 15;
    int e = __builtin_amdgcn_readfirstlane(rowptr[node]);
    int end = e + __builtin_amdgcn_readfirstlane(deg[node]) - 1;
    float ax = 0.f, ay = 0.f, az = 0.f, aw = 0.f;
    float bx = 0.f, by = 0.f, bz = 0.f, bw = 0.f;
    for (; e + 8 <= end; e += 8) {
        int s0 = col[e + grp];
        int s1 = col[e + 4 + grp];
        ushort4 t0 = *(const ushort4*)(Tb + (size_t)s0 * HID + fl * 4);
        ushort4 t1 = *(const ushort4*)(Tb + (size_t)s1 * HID + fl * 4);
        ax += b2f(t0.x); ay += b2f(t0.y); az += b2f(t0.z); aw += b2f(t0.w);
        bx += b2f(t1.x); by += b2f(t1.y); bz += b2f(t1.z); bw += b2f(t1.w);
    }
    for (; e < end; e += 4) {
        int idx = e + grp;
        if (idx < end) {
            int s = col[idx];
            ushort4 tv = *(const ushort4*)(Tb + (size_t)s * HID + fl * 4);
            ax += b2f(tv.x); ay += b2f(tv.y); az += b2f(tv.z); aw += b2f(tv.w);
        }
    }
    ax += bx; ay += by; az += bz; aw += bw;
    ax += __shfl_xor(ax, 16); ay += __shfl_xor(ay, 16);
    az += __shfl_xor(az, 16); aw += __shfl_xor(aw, 16);
    ax += __shfl_xor(ax, 32); ay += __shfl_xor(ay, 32);
    az += __shfl_xor(az, 32); aw += __shfl_xor(aw, 32);
    ushort4 sv = *(const ushort4*)(Tb + (size_t)node * HID + fl * 4);
    ax += b2f(sv.x); ay += b2f(sv.y); az += b2f(sv.z); aw += b2f(sv.w);
    float di = dinv[node];
    float4 bs = *(const float4*)(bias + fl * 4);
    ax = fmaf(di, ax, bs.x);
    ay = fmaf(di, ay, bs.y);
    az = fmaf(di, az, bs.z);
    aw = fmaf(di, aw, bs.w);
    float4 wl = *(const float4*)(Wl + fl * 4);
    float s = ax * wl.x + ay * wl.y + az * wl.z + aw * wl.w;
    s += __shfl_xor(s, 1);
    s += __shfl_xor(s, 2);
    s += __shfl_xor(s, 4);
    s += __shfl_xor(s, 8);
    if (lane == 0)
        atomicAdd(&partial[(blockIdx.x & (NPART - 1)) * PSTRIDE + batch[node]], s);
}

__global__ void k_pool_reduce(const float* __restrict__ partial,
                              const float* __restrict__ bl,
                              float* __restrict__ out) {
    int g = threadIdx.x;
    if (g >= N_GRAPHS) return;
    float s = bl[0];
    for (int p = 0; p < NPART; ++p) s += partial[p * PSTRIDE + g];
    out[g] = s;
}

extern "C" void kernel_launch(void* const* d_in, const int* in_sizes, int n_in,
                              void* d_out, int out_size, void* d_ws, size_t ws_size,
                              hipStream_t stream) {
    const float* x     = (const float*)d_in[0];
    const int*   ei    = (const int*)d_in[1];
    const int*   batch = (const int*)d_in[2];
    const float* W1    = (const float*)d_in[3];
    const float* b1    = (const float*)d_in[4];
    const float* W2    = (const float*)d_in[5];
    const float* b2    = (const float*)d_in[6];
    const float* W3    = (const float*)d_in[7];
    const float* b3    = (const float*)d_in[8];
    const float* Wl    = (const float*)d_in[9];
    const float* bl    = (const float*)d_in[10];
    float* out = (float*)d_out;

    char* p = (char*)d_ws;
    unsigned short* tb = (unsigned short*)p; p += (size_t)N_NODES * HID * 2;  // 12.8 MB
    unsigned short* hB = (unsigned short*)p; p += (size_t)N_NODES * HID * 2;  // 12.8 MB
    int*   col     = (int*)p;   p += (size_t)(N_EDGES + 16) * 4;              // 6.4 MB
    int*   ebuck   = (int*)p;   p += (size_t)N_EDGES * 4;                     // 6.4 MB
    int*   deg     = (int*)p;   p += (size_t)N_NODES * 4;
    float* dinv    = (float*)p; p += (size_t)N_NODES * 4;
    int*   rowptr  = (int*)p;   p += (size_t)N_NODES * 4;
    int*   bcount  = (int*)p;   p += (NBUCK + 1) * 4;
    int*   bstart  = (int*)p;   p += (NBUCK + 1) * 4;
    int*   bfill   = (int*)p;   p += (NBUCK + 1) * 4;
    int*   bsum    = (int*)p;   p += 512 * 4;
    int*   bscan   = (int*)p;   p += 512 * 4;
    float* partial = (float*)p; p += (size_t)NPART * PSTRIDE * 4;
    unsigned short* wt1 = (unsigned short*)p; p += (size_t)IN_DIM * HID * 2;
    unsigned short* wt2 = (unsigned short*)p; p += (size_t)HID * HID * 2;
    unsigned short* wt3 = (unsigned short*)p; p += (size_t)HID * HID * 2;

    const int* src  = ei;
    const int* dstp = ei + N_EDGES;

    const int nb = (N_NODES + 255) / 256;            // 391
    const int cb = (N_EDGES + CHUNK - 1) / CHUNK;    // 391
    const int gemm_blocks = (N_NODES + 63) / 64;     // 1563
    const int node_wave_blocks = (N_NODES + 3) / 4;  // 25000

    k_wprep<<<(IN_DIM * HID + 255) / 256, 256, 0, stream>>>(W1, W2, W3, wt1, wt2, wt3);
    k_zero_misc<<<(NPART * PSTRIDE + 255) / 256, 256, 0, stream>>>(bcount, partial);
    k_bhist<<<cb, 256, 0, stream>>>(dstp, bcount);
    k_bscan<<<1, 512, 0, stream>>>(bcount, bstart, bfill);
    k_bscatter<<<cb, 256, 0, stream>>>(src, dstp, bfill, ebuck);
    k_deg<<<NBUCK, 256, 0, stream>>>(bstart, ebuck, deg);
    k_scan1<<<nb, 256, 0, stream>>>(deg, dinv, bsum);
    k_scan2<<<1, 512, 0, stream>>>(bsum, bscan, nb);
    k_scan3<<<nb, 256, 0, stream>>>(deg, bscan, rowptr);
    k_fill<<<NBUCK, 256, 0, stream>>>(bstart, ebuck, rowptr, col);

    k_gemm1<<<gemm_blocks, 256, 0, stream>>>(x, wt1, dinv, tb);
    k_agg<<<node_wave_blocks, 256, 0, stream>>>(tb, rowptr, deg, dinv, col, b1, hB);
    k_gemm2<<<gemm_blocks, 256, 0, stream>>>(hB, wt2, dinv, tb);
    k_agg<<<node_wave_blocks, 256, 0, stream>>>(tb, rowptr, deg, dinv, col, b2, hB);
    k_gemm2<<<gemm_blocks, 256, 0, stream>>>(hB, wt3, dinv, tb);
    k_agg_pool<<<node_wave_blocks, 256, 0, stream>>>(tb, rowptr, deg, dinv, col, b3,
                                                     Wl, batch, partial);

    k_pool_reduce<<<1, 128, 0, stream>>>(partial, bl, out);
}